// Round 1
// baseline (1195.807 us; speedup 1.0000x reference)
//
#include <hip/hip_runtime.h>
#include <math.h>

#define L_ 32
#define B_ 4
#define N_ 1000
#define D_ 128
#define H_ 8
#define DH_ 16
#define KN_ 8
#define M_ (L_ * B_ * N_)  // 128000 rows

// ---------------------------------------------------------------------------
// Projection GEMM: out(M,384) = x(M,128) @ W(384,128)^T + bias(384)
// Block: 384 threads, 16 rows. x tile staged transposed in LDS; each thread
// owns one output column j (= one W row, 512B, L1-resident across k-loop).
// LDS reads are full-wave broadcasts (all lanes read the same float4).
// ---------------------------------------------------------------------------
__global__ __launch_bounds__(384) void proj_kernel(
    const float* __restrict__ x, const float* __restrict__ w,
    const float* __restrict__ bias, float* __restrict__ out) {
  __shared__ float xs[128][36];  // [k][r], pad 36 (16B-aligned rows)
  const int t = threadIdx.x;
  const int r0 = blockIdx.x * 16;
  for (int e = t; e < 16 * 128; e += 384) {
    int r = e >> 7, k = e & 127;
    xs[k][r] = x[(size_t)(r0 + r) * D_ + k];
  }
  __syncthreads();
  const float* wrow = w + (size_t)t * D_;
  float acc[16];
#pragma unroll
  for (int i = 0; i < 16; ++i) acc[i] = 0.f;
#pragma unroll 4
  for (int k = 0; k < D_; ++k) {
    float wv = wrow[k];
    const float4* xr = (const float4*)(&xs[k][0]);
#pragma unroll
    for (int r4 = 0; r4 < 4; ++r4) {
      float4 xv = xr[r4];
      acc[r4 * 4 + 0] = fmaf(wv, xv.x, acc[r4 * 4 + 0]);
      acc[r4 * 4 + 1] = fmaf(wv, xv.y, acc[r4 * 4 + 1]);
      acc[r4 * 4 + 2] = fmaf(wv, xv.z, acc[r4 * 4 + 2]);
      acc[r4 * 4 + 3] = fmaf(wv, xv.w, acc[r4 * 4 + 3]);
    }
  }
  float bv = bias[t];
#pragma unroll
  for (int r = 0; r < 16; ++r)
    out[(size_t)(r0 + r) * 384 + t] = acc[r] + bv;
}

// ---------------------------------------------------------------------------
// Temporal attention + out-projection, fused. One block per (b,n).
// qkv rows for l=0..31 share (b,n). Softmax over m (32). Then o @ Wout^T + b.
// ---------------------------------------------------------------------------
__global__ __launch_bounds__(256) void tattn_fused_kernel(
    const float* __restrict__ qkv, const float* __restrict__ wout,
    const float* __restrict__ bout, float* __restrict__ out) {
  __shared__ float skv[32][264];  // k cols 0..127, v cols 128..255 (pad 264)
  __shared__ float osT[128][36];  // o transposed [d][l]
  const int t = threadIdx.x;
  const int b = blockIdx.x / N_;
  const int n = blockIdx.x % N_;
  // stage k,v (32 rows x 256 floats)
  for (int e = t; e < 32 * 64; e += 256) {
    int l = e >> 6, c4 = e & 63;
    size_t row = ((size_t)(l * B_ + b) * N_ + n) * 384 + 128;
    float4 v = ((const float4*)(qkv + row))[c4];
    ((float4*)(&skv[l][0]))[c4] = v;
  }
  __syncthreads();
  {
    const int h = t >> 5, l = t & 31;
    float q[16];
    {
      const float4* qp =
          (const float4*)(qkv + ((size_t)(l * B_ + b) * N_ + n) * 384 + h * DH_);
#pragma unroll
      for (int i = 0; i < 4; ++i) {
        float4 v = qp[i];
        q[4 * i + 0] = v.x; q[4 * i + 1] = v.y;
        q[4 * i + 2] = v.z; q[4 * i + 3] = v.w;
      }
    }
    float sc[32];
    float mx = -1e30f;
#pragma unroll
    for (int m = 0; m < 32; ++m) {
      const float4* kp = (const float4*)(&skv[m][h * DH_]);
      float d = 0.f;
#pragma unroll
      for (int i = 0; i < 4; ++i) {
        float4 kv = kp[i];
        d = fmaf(q[4 * i + 0], kv.x, d);
        d = fmaf(q[4 * i + 1], kv.y, d);
        d = fmaf(q[4 * i + 2], kv.z, d);
        d = fmaf(q[4 * i + 3], kv.w, d);
      }
      d *= 0.25f;  // 1/sqrt(16)
      sc[m] = d;
      mx = fmaxf(mx, d);
    }
    float ssum = 0.f;
#pragma unroll
    for (int m = 0; m < 32; ++m) { sc[m] = __expf(sc[m] - mx); ssum += sc[m]; }
    float inv = 1.f / ssum;
    float oa[16];
#pragma unroll
    for (int i = 0; i < 16; ++i) oa[i] = 0.f;
#pragma unroll
    for (int m = 0; m < 32; ++m) {
      float p = sc[m] * inv;
      const float4* vp = (const float4*)(&skv[m][128 + h * DH_]);
#pragma unroll
      for (int i = 0; i < 4; ++i) {
        float4 vv = vp[i];
        oa[4 * i + 0] = fmaf(p, vv.x, oa[4 * i + 0]);
        oa[4 * i + 1] = fmaf(p, vv.y, oa[4 * i + 1]);
        oa[4 * i + 2] = fmaf(p, vv.z, oa[4 * i + 2]);
        oa[4 * i + 3] = fmaf(p, vv.w, oa[4 * i + 3]);
      }
    }
#pragma unroll
    for (int i = 0; i < 16; ++i) osT[h * DH_ + i][l] = oa[i];
  }
  __syncthreads();
  {  // out-projection: 32 rows x 128 cols
    const int j = t & 127, half = t >> 7;
    const float* wrow = wout + (size_t)j * D_;
    float acc[16];
#pragma unroll
    for (int i = 0; i < 16; ++i) acc[i] = 0.f;
#pragma unroll 4
    for (int k = 0; k < D_; ++k) {
      float wv = wrow[k];
      const float4* op = (const float4*)(&osT[k][half * 16]);
#pragma unroll
      for (int r4 = 0; r4 < 4; ++r4) {
        float4 ov = op[r4];
        acc[r4 * 4 + 0] = fmaf(wv, ov.x, acc[r4 * 4 + 0]);
        acc[r4 * 4 + 1] = fmaf(wv, ov.y, acc[r4 * 4 + 1]);
        acc[r4 * 4 + 2] = fmaf(wv, ov.z, acc[r4 * 4 + 2]);
        acc[r4 * 4 + 3] = fmaf(wv, ov.w, acc[r4 * 4 + 3]);
      }
    }
    float bv = bout[j];
#pragma unroll
    for (int r = 0; r < 16; ++r) {
      int l = half * 16 + r;
      out[((size_t)(l * B_ + b) * N_ + n) * D_ + j] = acc[r] + bv;
    }
  }
}

// ---------------------------------------------------------------------------
// Spatial attention + out-projection, fused & accumulated into out.
// One block per 32 consecutive rows r=(l*B+b)*N+n. Gathers neighbors'
// projected k/v from qkv_s (gather-after-projection == reference bit-exactly).
// ---------------------------------------------------------------------------
__global__ __launch_bounds__(256) void sattn_fused_kernel(
    const float* __restrict__ qkv, const int* __restrict__ route,
    const float* __restrict__ wout, const float* __restrict__ bout,
    float* __restrict__ out) {
  __shared__ float osT[128][36];
  const int t = threadIdx.x;
  const int r0 = blockIdx.x * 32;
  {
    const int rl = t >> 3, h = t & 7;
    const int r = r0 + rl;
    const int n = r % N_;
    const int lb = r / N_;  // l*B+b
    float q[16];
    {
      const float4* qp = (const float4*)(qkv + (size_t)r * 384 + h * DH_);
#pragma unroll
      for (int i = 0; i < 4; ++i) {
        float4 v = qp[i];
        q[4 * i + 0] = v.x; q[4 * i + 1] = v.y;
        q[4 * i + 2] = v.z; q[4 * i + 3] = v.w;
      }
    }
    int nb[KN_];
#pragma unroll
    for (int kk = 0; kk < KN_; ++kk) nb[kk] = route[n * KN_ + kk];
    float sc[KN_];
    float mx = -1e30f;
#pragma unroll
    for (int kk = 0; kk < KN_; ++kk) {
      const float4* kp = (const float4*)(qkv + ((size_t)lb * N_ + nb[kk]) * 384 +
                                         128 + h * DH_);
      float d = 0.f;
#pragma unroll
      for (int i = 0; i < 4; ++i) {
        float4 kv = kp[i];
        d = fmaf(q[4 * i + 0], kv.x, d);
        d = fmaf(q[4 * i + 1], kv.y, d);
        d = fmaf(q[4 * i + 2], kv.z, d);
        d = fmaf(q[4 * i + 3], kv.w, d);
      }
      d *= 0.25f;
      sc[kk] = d;
      mx = fmaxf(mx, d);
    }
    float ssum = 0.f;
#pragma unroll
    for (int kk = 0; kk < KN_; ++kk) { sc[kk] = __expf(sc[kk] - mx); ssum += sc[kk]; }
    float inv = 1.f / ssum;
    float oa[16];
#pragma unroll
    for (int i = 0; i < 16; ++i) oa[i] = 0.f;
#pragma unroll
    for (int kk = 0; kk < KN_; ++kk) {
      float p = sc[kk] * inv;
      const float4* vp = (const float4*)(qkv + ((size_t)lb * N_ + nb[kk]) * 384 +
                                         256 + h * DH_);
#pragma unroll
      for (int i = 0; i < 4; ++i) {
        float4 vv = vp[i];
        oa[4 * i + 0] = fmaf(p, vv.x, oa[4 * i + 0]);
        oa[4 * i + 1] = fmaf(p, vv.y, oa[4 * i + 1]);
        oa[4 * i + 2] = fmaf(p, vv.z, oa[4 * i + 2]);
        oa[4 * i + 3] = fmaf(p, vv.w, oa[4 * i + 3]);
      }
    }
#pragma unroll
    for (int i = 0; i < 16; ++i) osT[h * DH_ + i][rl] = oa[i];
  }
  __syncthreads();
  {  // out-projection, accumulate into out (t_out already written)
    const int j = t & 127, half = t >> 7;
    const float* wrow = wout + (size_t)j * D_;
    float acc[16];
#pragma unroll
    for (int i = 0; i < 16; ++i) acc[i] = 0.f;
#pragma unroll 4
    for (int k = 0; k < D_; ++k) {
      float wv = wrow[k];
      const float4* op = (const float4*)(&osT[k][half * 16]);
#pragma unroll
      for (int r4 = 0; r4 < 4; ++r4) {
        float4 ov = op[r4];
        acc[r4 * 4 + 0] = fmaf(wv, ov.x, acc[r4 * 4 + 0]);
        acc[r4 * 4 + 1] = fmaf(wv, ov.y, acc[r4 * 4 + 1]);
        acc[r4 * 4 + 2] = fmaf(wv, ov.z, acc[r4 * 4 + 2]);
        acc[r4 * 4 + 3] = fmaf(wv, ov.w, acc[r4 * 4 + 3]);
      }
    }
    float bv = bout[j];
#pragma unroll
    for (int r = 0; r < 16; ++r) {
      size_t idx = (size_t)(r0 + half * 16 + r) * D_ + j;
      out[idx] += acc[r] + bv;
    }
  }
}

extern "C" void kernel_launch(void* const* d_in, const int* in_sizes, int n_in,
                              void* d_out, int out_size, void* d_ws,
                              size_t ws_size, hipStream_t stream) {
  const float* x = (const float*)d_in[0];
  const int* route = (const int*)d_in[1];
  const float* t_in_w = (const float*)d_in[2];
  const float* t_in_b = (const float*)d_in[3];
  const float* t_out_w = (const float*)d_in[4];
  const float* t_out_b = (const float*)d_in[5];
  const float* s_in_w = (const float*)d_in[6];
  const float* s_in_b = (const float*)d_in[7];
  const float* s_out_w = (const float*)d_in[8];
  const float* s_out_b = (const float*)d_in[9];
  // d_in[10] = n_heads (==8, hardcoded)
  float* out = (float*)d_out;
  float* qkv = (float*)d_ws;  // needs M*384*4 = 196,608,000 bytes

  // temporal branch
  proj_kernel<<<M_ / 16, 384, 0, stream>>>(x, t_in_w, t_in_b, qkv);
  tattn_fused_kernel<<<B_ * N_, 256, 0, stream>>>(qkv, t_out_w, t_out_b, out);
  // spatial branch (reuses qkv buffer)
  proj_kernel<<<M_ / 16, 384, 0, stream>>>(x, s_in_w, s_in_b, qkv);
  sattn_fused_kernel<<<M_ / 32, 256, 0, stream>>>(qkv, route, s_out_w, s_out_b,
                                                  out);
}

// Round 3
// 681.884 us; speedup vs baseline: 1.7537x; 1.7537x over previous
//
#include <hip/hip_runtime.h>
#include <math.h>

#define L_ 32
#define B_ 4
#define N_ 1000
#define D_ 128
#define H_ 8
#define DH_ 16
#define KN_ 8
#define M_ (L_ * B_ * N_)  // 128000 rows

typedef __attribute__((ext_vector_type(8))) short short8;
typedef __attribute__((ext_vector_type(4))) float floatx4;

static __device__ __forceinline__ unsigned short f2bf(float f) {
  union { float f; unsigned u; } v; v.f = f;
  unsigned r = v.u + 0x7fffu + ((v.u >> 16) & 1u);
  return (unsigned short)(r >> 16);
}

// ---------------------------------------------------------------------------
// proj_mfma: out(M,384) = x(M,128) @ W(384,128)^T + bias(384), bf16 MFMA.
// Grid: (M/128)*3 blocks of 256 threads. Per block: 128(M)x128(N) tile,
// K=128 in 4 chunks of 32. LDS: A,B tiles as bf16, XOR-swizzled 16B granules
// (16 granules/row; pos = m*16 + (g ^ (m&7))) -> <=2-way bank aliasing (free).
// Each wave computes 64x64 via 4x4 grid of 16x16x32 MFMAs.
// R3 fix: staging loop covers all 4096 float4 per tile (was 1024 -> NaN).
// ---------------------------------------------------------------------------
__global__ __launch_bounds__(256) void proj_mfma(
    const float* __restrict__ x, const float* __restrict__ w,
    const float* __restrict__ bias, float* __restrict__ out) {
  __shared__ unsigned short As[128 * 128];  // 32 KB
  __shared__ unsigned short Bs[128 * 128];  // 32 KB
  const int t = threadIdx.x;
  const int bm = blockIdx.x / 3, bn = blockIdx.x % 3;
  const float* aSrc = x + (size_t)bm * 128 * 128;
  const float* bSrc = w + (size_t)bn * 128 * 128;
  // stage + fp32->bf16 convert + swizzle. 4096 float4 per tile, 16 iters x 256.
#pragma unroll
  for (int it = 0; it < 16; ++it) {
    int f = it * 256 + t;        // float4 index; row m = f>>5 (32 float4/row)
    int m = f >> 5, c4 = f & 31;
    int g = c4 >> 1, half = c4 & 1;           // granule (8 bf16), half (4 bf16)
    int p = m * 16 + (g ^ (m & 7));           // swizzled granule position
    float4 av = ((const float4*)aSrc)[f];
    float4 bv = ((const float4*)bSrc)[f];
    ushort4 a4 = make_ushort4(f2bf(av.x), f2bf(av.y), f2bf(av.z), f2bf(av.w));
    ushort4 b4 = make_ushort4(f2bf(bv.x), f2bf(bv.y), f2bf(bv.z), f2bf(bv.w));
    *(ushort4*)(&As[p * 8 + half * 4]) = a4;
    *(ushort4*)(&Bs[p * 8 + half * 4]) = b4;
  }
  __syncthreads();
  const int wave = t >> 6, lane = t & 63;
  const int wm = (wave >> 1) * 64, wn = (wave & 1) * 64;
  const int lq = lane >> 4, l16 = lane & 15;
  floatx4 acc[4][4] = {};
#pragma unroll
  for (int kk = 0; kk < 4; ++kk) {  // k0 = kk*32
    int g = kk * 4 + lq;            // this quad's 16B granule within the row
    short8 a[4], b[4];
#pragma unroll
    for (int i = 0; i < 4; ++i) {
      int ma = wm + i * 16 + l16;
      a[i] = *(const short8*)(&As[(ma * 16 + (g ^ (ma & 7))) * 8]);
      int nb = wn + i * 16 + l16;
      b[i] = *(const short8*)(&Bs[(nb * 16 + (g ^ (nb & 7))) * 8]);
    }
#pragma unroll
    for (int i = 0; i < 4; ++i)
#pragma unroll
      for (int j = 0; j < 4; ++j)
        acc[i][j] = __builtin_amdgcn_mfma_f32_16x16x32_bf16(a[i], b[j],
                                                            acc[i][j], 0, 0, 0);
  }
  // epilogue: D row (M) = wm + i*16 + lq*4 + r, col (N) = wn + j*16 + l16
  const size_t rowBase = (size_t)bm * 128 + wm;
  const int colBase = bn * 128 + wn;
#pragma unroll
  for (int j = 0; j < 4; ++j) {
    float bb = bias[colBase + j * 16 + l16];
#pragma unroll
    for (int i = 0; i < 4; ++i) {
#pragma unroll
      for (int r = 0; r < 4; ++r) {
        size_t row = rowBase + i * 16 + lq * 4 + r;
        out[row * 384 + colBase + j * 16 + l16] = acc[i][j][r] + bb;
      }
    }
  }
}

// ---------------------------------------------------------------------------
// Temporal attention + out-projection, fused. One block per (b,n).
// ---------------------------------------------------------------------------
__global__ __launch_bounds__(256) void tattn_fused_kernel(
    const float* __restrict__ qkv, const float* __restrict__ wout,
    const float* __restrict__ bout, float* __restrict__ out) {
  __shared__ float skv[32][264];  // k cols 0..127, v cols 128..255 (pad 264)
  __shared__ float osT[128][36];  // o transposed [d][l]
  const int t = threadIdx.x;
  const int b = blockIdx.x / N_;
  const int n = blockIdx.x % N_;
  for (int e = t; e < 32 * 64; e += 256) {
    int l = e >> 6, c4 = e & 63;
    size_t row = ((size_t)(l * B_ + b) * N_ + n) * 384 + 128;
    float4 v = ((const float4*)(qkv + row))[c4];
    ((float4*)(&skv[l][0]))[c4] = v;
  }
  __syncthreads();
  {
    const int h = t >> 5, l = t & 31;
    float q[16];
    {
      const float4* qp =
          (const float4*)(qkv + ((size_t)(l * B_ + b) * N_ + n) * 384 + h * DH_);
#pragma unroll
      for (int i = 0; i < 4; ++i) {
        float4 v = qp[i];
        q[4 * i + 0] = v.x; q[4 * i + 1] = v.y;
        q[4 * i + 2] = v.z; q[4 * i + 3] = v.w;
      }
    }
    float sc[32];
    float mx = -1e30f;
#pragma unroll
    for (int m = 0; m < 32; ++m) {
      const float4* kp = (const float4*)(&skv[m][h * DH_]);
      float d = 0.f;
#pragma unroll
      for (int i = 0; i < 4; ++i) {
        float4 kv = kp[i];
        d = fmaf(q[4 * i + 0], kv.x, d);
        d = fmaf(q[4 * i + 1], kv.y, d);
        d = fmaf(q[4 * i + 2], kv.z, d);
        d = fmaf(q[4 * i + 3], kv.w, d);
      }
      d *= 0.25f;
      sc[m] = d;
      mx = fmaxf(mx, d);
    }
    float ssum = 0.f;
#pragma unroll
    for (int m = 0; m < 32; ++m) { sc[m] = __expf(sc[m] - mx); ssum += sc[m]; }
    float inv = 1.f / ssum;
    float oa[16];
#pragma unroll
    for (int i = 0; i < 16; ++i) oa[i] = 0.f;
#pragma unroll
    for (int m = 0; m < 32; ++m) {
      float p = sc[m] * inv;
      const float4* vp = (const float4*)(&skv[m][128 + h * DH_]);
#pragma unroll
      for (int i = 0; i < 4; ++i) {
        float4 vv = vp[i];
        oa[4 * i + 0] = fmaf(p, vv.x, oa[4 * i + 0]);
        oa[4 * i + 1] = fmaf(p, vv.y, oa[4 * i + 1]);
        oa[4 * i + 2] = fmaf(p, vv.z, oa[4 * i + 2]);
        oa[4 * i + 3] = fmaf(p, vv.w, oa[4 * i + 3]);
      }
    }
#pragma unroll
    for (int i = 0; i < 16; ++i) osT[h * DH_ + i][l] = oa[i];
  }
  __syncthreads();
  {
    const int j = t & 127, half = t >> 7;
    const float* wrow = wout + (size_t)j * D_;
    float acc[16];
#pragma unroll
    for (int i = 0; i < 16; ++i) acc[i] = 0.f;
#pragma unroll 4
    for (int k = 0; k < D_; ++k) {
      float wv = wrow[k];
      const float4* op = (const float4*)(&osT[k][half * 16]);
#pragma unroll
      for (int r4 = 0; r4 < 4; ++r4) {
        float4 ov = op[r4];
        acc[r4 * 4 + 0] = fmaf(wv, ov.x, acc[r4 * 4 + 0]);
        acc[r4 * 4 + 1] = fmaf(wv, ov.y, acc[r4 * 4 + 1]);
        acc[r4 * 4 + 2] = fmaf(wv, ov.z, acc[r4 * 4 + 2]);
        acc[r4 * 4 + 3] = fmaf(wv, ov.w, acc[r4 * 4 + 3]);
      }
    }
    float bv = bout[j];
#pragma unroll
    for (int r = 0; r < 16; ++r) {
      int l = half * 16 + r;
      out[((size_t)(l * B_ + b) * N_ + n) * D_ + j] = acc[r] + bv;
    }
  }
}

// ---------------------------------------------------------------------------
// Spatial attention + out-projection, fused & accumulated into out.
// ---------------------------------------------------------------------------
__global__ __launch_bounds__(256) void sattn_fused_kernel(
    const float* __restrict__ qkv, const int* __restrict__ route,
    const float* __restrict__ wout, const float* __restrict__ bout,
    float* __restrict__ out) {
  __shared__ float osT[128][36];
  const int t = threadIdx.x;
  const int r0 = blockIdx.x * 32;
  {
    const int rl = t >> 3, h = t & 7;
    const int r = r0 + rl;
    const int n = r % N_;
    const int lb = r / N_;  // l*B+b
    float q[16];
    {
      const float4* qp = (const float4*)(qkv + (size_t)r * 384 + h * DH_);
#pragma unroll
      for (int i = 0; i < 4; ++i) {
        float4 v = qp[i];
        q[4 * i + 0] = v.x; q[4 * i + 1] = v.y;
        q[4 * i + 2] = v.z; q[4 * i + 3] = v.w;
      }
    }
    int nb[KN_];
#pragma unroll
    for (int kk = 0; kk < KN_; ++kk) nb[kk] = route[n * KN_ + kk];
    float sc[KN_];
    float mx = -1e30f;
#pragma unroll
    for (int kk = 0; kk < KN_; ++kk) {
      const float4* kp = (const float4*)(qkv + ((size_t)lb * N_ + nb[kk]) * 384 +
                                         128 + h * DH_);
      float d = 0.f;
#pragma unroll
      for (int i = 0; i < 4; ++i) {
        float4 kv = kp[i];
        d = fmaf(q[4 * i + 0], kv.x, d);
        d = fmaf(q[4 * i + 1], kv.y, d);
        d = fmaf(q[4 * i + 2], kv.z, d);
        d = fmaf(q[4 * i + 3], kv.w, d);
      }
      d *= 0.25f;
      sc[kk] = d;
      mx = fmaxf(mx, d);
    }
    float ssum = 0.f;
#pragma unroll
    for (int kk = 0; kk < KN_; ++kk) { sc[kk] = __expf(sc[kk] - mx); ssum += sc[kk]; }
    float inv = 1.f / ssum;
    float oa[16];
#pragma unroll
    for (int i = 0; i < 16; ++i) oa[i] = 0.f;
#pragma unroll
    for (int kk = 0; kk < KN_; ++kk) {
      float p = sc[kk] * inv;
      const float4* vp = (const float4*)(qkv + ((size_t)lb * N_ + nb[kk]) * 384 +
                                         256 + h * DH_);
#pragma unroll
      for (int i = 0; i < 4; ++i) {
        float4 vv = vp[i];
        oa[4 * i + 0] = fmaf(p, vv.x, oa[4 * i + 0]);
        oa[4 * i + 1] = fmaf(p, vv.y, oa[4 * i + 1]);
        oa[4 * i + 2] = fmaf(p, vv.z, oa[4 * i + 2]);
        oa[4 * i + 3] = fmaf(p, vv.w, oa[4 * i + 3]);
      }
    }
#pragma unroll
    for (int i = 0; i < 16; ++i) osT[h * DH_ + i][rl] = oa[i];
  }
  __syncthreads();
  {
    const int j = t & 127, half = t >> 7;
    const float* wrow = wout + (size_t)j * D_;
    float acc[16];
#pragma unroll
    for (int i = 0; i < 16; ++i) acc[i] = 0.f;
#pragma unroll 4
    for (int k = 0; k < D_; ++k) {
      float wv = wrow[k];
      const float4* op = (const float4*)(&osT[k][half * 16]);
#pragma unroll
      for (int r4 = 0; r4 < 4; ++r4) {
        float4 ov = op[r4];
        acc[r4 * 4 + 0] = fmaf(wv, ov.x, acc[r4 * 4 + 0]);
        acc[r4 * 4 + 1] = fmaf(wv, ov.y, acc[r4 * 4 + 1]);
        acc[r4 * 4 + 2] = fmaf(wv, ov.z, acc[r4 * 4 + 2]);
        acc[r4 * 4 + 3] = fmaf(wv, ov.w, acc[r4 * 4 + 3]);
      }
    }
    float bv = bout[j];
#pragma unroll
    for (int r = 0; r < 16; ++r) {
      size_t idx = (size_t)(r0 + half * 16 + r) * D_ + j;
      out[idx] += acc[r] + bv;
    }
  }
}

extern "C" void kernel_launch(void* const* d_in, const int* in_sizes, int n_in,
                              void* d_out, int out_size, void* d_ws,
                              size_t ws_size, hipStream_t stream) {
  const float* x = (const float*)d_in[0];
  const int* route = (const int*)d_in[1];
  const float* t_in_w = (const float*)d_in[2];
  const float* t_in_b = (const float*)d_in[3];
  const float* t_out_w = (const float*)d_in[4];
  const float* t_out_b = (const float*)d_in[5];
  const float* s_in_w = (const float*)d_in[6];
  const float* s_in_b = (const float*)d_in[7];
  const float* s_out_w = (const float*)d_in[8];
  const float* s_out_b = (const float*)d_in[9];
  float* out = (float*)d_out;
  float* qkv = (float*)d_ws;  // M*384*4 = 196,608,000 bytes

  proj_mfma<<<(M_ / 128) * 3, 256, 0, stream>>>(x, t_in_w, t_in_b, qkv);
  tattn_fused_kernel<<<B_ * N_, 256, 0, stream>>>(qkv, t_out_w, t_out_b, out);
  proj_mfma<<<(M_ / 128) * 3, 256, 0, stream>>>(x, s_in_w, s_in_b, qkv);
  sattn_fused_kernel<<<M_ / 32, 256, 0, stream>>>(qkv, route, s_out_w, s_out_b,
                                                  out);
}

// Round 4
// 388.758 us; speedup vs baseline: 3.0760x; 1.7540x over previous
//
#include <hip/hip_runtime.h>
#include <math.h>

#define L_ 32
#define B_ 4
#define N_ 1000
#define D_ 128
#define H_ 8
#define DH_ 16
#define KN_ 8
#define M_ (L_ * B_ * N_)  // 128000 rows

typedef __attribute__((ext_vector_type(8))) short short8;
typedef __attribute__((ext_vector_type(8))) unsigned short ushort8v;
typedef __attribute__((ext_vector_type(4))) float floatx4;

static __device__ __forceinline__ unsigned short f2bf(float f) {
  union { float f; unsigned u; } v; v.f = f;
  unsigned r = v.u + 0x7fffu + ((v.u >> 16) & 1u);
  return (unsigned short)(r >> 16);
}
static __device__ __forceinline__ float bf2f(unsigned short s) {
  union { unsigned u; float f; } v; v.u = ((unsigned)s) << 16;
  return v.f;
}

// ---------------------------------------------------------------------------
// proj_mfma: qkv(M,384) bf16 = x(M,128) @ W(384,128)^T + bias, bf16 MFMA.
// 128x128 tile/block, XOR-swizzled LDS (<=2-way bank aliasing = free).
// ---------------------------------------------------------------------------
__global__ __launch_bounds__(256) void proj_mfma(
    const float* __restrict__ x, const float* __restrict__ w,
    const float* __restrict__ bias, unsigned short* __restrict__ out) {
  __shared__ unsigned short As[128 * 128];
  __shared__ unsigned short Bs[128 * 128];
  const int t = threadIdx.x;
  const int bm = blockIdx.x / 3, bn = blockIdx.x % 3;
  const float* aSrc = x + (size_t)bm * 128 * 128;
  const float* bSrc = w + (size_t)bn * 128 * 128;
#pragma unroll
  for (int it = 0; it < 16; ++it) {
    int f = it * 256 + t;  // float4 index; m = f>>5 (32 float4/row)
    int m = f >> 5, c4 = f & 31;
    int g = c4 >> 1, half = c4 & 1;
    int p = m * 16 + (g ^ (m & 7));
    float4 av = ((const float4*)aSrc)[f];
    float4 bv = ((const float4*)bSrc)[f];
    ushort4 a4 = make_ushort4(f2bf(av.x), f2bf(av.y), f2bf(av.z), f2bf(av.w));
    ushort4 b4 = make_ushort4(f2bf(bv.x), f2bf(bv.y), f2bf(bv.z), f2bf(bv.w));
    *(ushort4*)(&As[p * 8 + half * 4]) = a4;
    *(ushort4*)(&Bs[p * 8 + half * 4]) = b4;
  }
  __syncthreads();
  const int wave = t >> 6, lane = t & 63;
  const int wm = (wave >> 1) * 64, wn = (wave & 1) * 64;
  const int lq = lane >> 4, l16 = lane & 15;
  floatx4 acc[4][4] = {};
#pragma unroll
  for (int kk = 0; kk < 4; ++kk) {
    int g = kk * 4 + lq;
    short8 a[4], b[4];
#pragma unroll
    for (int i = 0; i < 4; ++i) {
      int ma = wm + i * 16 + l16;
      a[i] = *(const short8*)(&As[(ma * 16 + (g ^ (ma & 7))) * 8]);
      int nb = wn + i * 16 + l16;
      b[i] = *(const short8*)(&Bs[(nb * 16 + (g ^ (nb & 7))) * 8]);
    }
#pragma unroll
    for (int i = 0; i < 4; ++i)
#pragma unroll
      for (int j = 0; j < 4; ++j)
        acc[i][j] = __builtin_amdgcn_mfma_f32_16x16x32_bf16(a[i], b[j],
                                                            acc[i][j], 0, 0, 0);
  }
  const size_t rowBase = (size_t)bm * 128 + wm;
  const int colBase = bn * 128 + wn;
#pragma unroll
  for (int j = 0; j < 4; ++j) {
    float bb = bias[colBase + j * 16 + l16];
#pragma unroll
    for (int i = 0; i < 4; ++i) {
#pragma unroll
      for (int r = 0; r < 4; ++r) {
        size_t row = rowBase + i * 16 + lq * 4 + r;
        out[row * 384 + colBase + j * 16 + l16] = f2bf(acc[i][j][r] + bb);
      }
    }
  }
}

// ---------------------------------------------------------------------------
// tattn: pure temporal attention, one block per (b,n). qkv bf16 in, o_t bf16.
// Threads: t = l*8 + h (rl = t>>3 is the query row l, h = t&7 the head).
// k/v staged as bf16 in LDS (16B/lane conflict-free writes).
// ---------------------------------------------------------------------------
__global__ __launch_bounds__(256) void tattn_kernel(
    const unsigned short* __restrict__ qkv, unsigned short* __restrict__ o_t) {
  __shared__ unsigned short skv[32][264];  // k: 0..127, v: 128..255 (+pad)
  const int t = threadIdx.x;
  const int b = blockIdx.x / N_;
  const int n = blockIdx.x % N_;
#pragma unroll
  for (int it = 0; it < 4; ++it) {
    int e = it * 256 + t;
    int l = e >> 5, c8 = e & 31;  // 32 ushort8 granules per row (k+v)
    size_t src = ((size_t)(l * B_ + b) * N_ + n) * 384 + 128 + c8 * 8;
    *(ushort8v*)(&skv[l][c8 * 8]) = *(const ushort8v*)(qkv + src);
  }
  __syncthreads();
  const int rl = t >> 3, h = t & 7;
  float q[16];
  {
    const unsigned short* qp =
        qkv + ((size_t)(rl * B_ + b) * N_ + n) * 384 + h * DH_;
    ushort8v q0 = *(const ushort8v*)qp;
    ushort8v q1 = *(const ushort8v*)(qp + 8);
#pragma unroll
    for (int i = 0; i < 8; ++i) { q[i] = bf2f(q0[i]); q[8 + i] = bf2f(q1[i]); }
  }
  float sc[32];
  float mx = -1e30f;
#pragma unroll
  for (int m = 0; m < 32; ++m) {
    const ushort8v k0 = *(const ushort8v*)(&skv[m][h * DH_]);
    const ushort8v k1 = *(const ushort8v*)(&skv[m][h * DH_ + 8]);
    float d = 0.f;
#pragma unroll
    for (int i = 0; i < 8; ++i) {
      d = fmaf(q[i], bf2f(k0[i]), d);
      d = fmaf(q[8 + i], bf2f(k1[i]), d);
    }
    d *= 0.25f;
    sc[m] = d;
    mx = fmaxf(mx, d);
  }
  float ssum = 0.f;
#pragma unroll
  for (int m = 0; m < 32; ++m) { sc[m] = __expf(sc[m] - mx); ssum += sc[m]; }
  float inv = 1.f / ssum;
  float oa[16];
#pragma unroll
  for (int i = 0; i < 16; ++i) oa[i] = 0.f;
#pragma unroll
  for (int m = 0; m < 32; ++m) {
    float p = sc[m] * inv;
    const ushort8v v0 = *(const ushort8v*)(&skv[m][128 + h * DH_]);
    const ushort8v v1 = *(const ushort8v*)(&skv[m][128 + h * DH_ + 8]);
#pragma unroll
    for (int i = 0; i < 8; ++i) {
      oa[i] = fmaf(p, bf2f(v0[i]), oa[i]);
      oa[8 + i] = fmaf(p, bf2f(v1[i]), oa[8 + i]);
    }
  }
  ushort8v w0, w1;
#pragma unroll
  for (int i = 0; i < 8; ++i) { w0[i] = f2bf(oa[i]); w1[i] = f2bf(oa[8 + i]); }
  size_t orow = ((size_t)(rl * B_ + b) * N_ + n) * 128 + h * DH_;
  *(ushort8v*)(o_t + orow) = w0;
  *(ushort8v*)(o_t + orow + 8) = w1;
}

// ---------------------------------------------------------------------------
// sattn: pure spatial attention (K=8 gather). One block per 32 rows.
// Gathers projected neighbor k/v (gather-after-projection == reference).
// ---------------------------------------------------------------------------
__global__ __launch_bounds__(256) void sattn_kernel(
    const unsigned short* __restrict__ qkv, const int* __restrict__ route,
    unsigned short* __restrict__ o_s) {
  const int t = threadIdx.x;
  const int r0 = blockIdx.x * 32;
  const int rl = t >> 3, h = t & 7;
  const int r = r0 + rl;
  const int n = r % N_;
  const int lb = r / N_;  // l*B+b
  float q[16];
  {
    const unsigned short* qp = qkv + (size_t)r * 384 + h * DH_;
    ushort8v q0 = *(const ushort8v*)qp;
    ushort8v q1 = *(const ushort8v*)(qp + 8);
#pragma unroll
    for (int i = 0; i < 8; ++i) { q[i] = bf2f(q0[i]); q[8 + i] = bf2f(q1[i]); }
  }
  int nb[KN_];
#pragma unroll
  for (int kk = 0; kk < KN_; ++kk) nb[kk] = route[n * KN_ + kk];
  float sc[KN_];
  float mx = -1e30f;
#pragma unroll
  for (int kk = 0; kk < KN_; ++kk) {
    const unsigned short* kp =
        qkv + ((size_t)lb * N_ + nb[kk]) * 384 + 128 + h * DH_;
    ushort8v k0 = *(const ushort8v*)kp;
    ushort8v k1 = *(const ushort8v*)(kp + 8);
    float d = 0.f;
#pragma unroll
    for (int i = 0; i < 8; ++i) {
      d = fmaf(q[i], bf2f(k0[i]), d);
      d = fmaf(q[8 + i], bf2f(k1[i]), d);
    }
    d *= 0.25f;
    sc[kk] = d;
    mx = fmaxf(mx, d);
  }
  float ssum = 0.f;
#pragma unroll
  for (int kk = 0; kk < KN_; ++kk) { sc[kk] = __expf(sc[kk] - mx); ssum += sc[kk]; }
  float inv = 1.f / ssum;
  float oa[16];
#pragma unroll
  for (int i = 0; i < 16; ++i) oa[i] = 0.f;
#pragma unroll
  for (int kk = 0; kk < KN_; ++kk) {
    float p = sc[kk] * inv;
    const unsigned short* vp =
        qkv + ((size_t)lb * N_ + nb[kk]) * 384 + 256 + h * DH_;
    ushort8v v0 = *(const ushort8v*)vp;
    ushort8v v1 = *(const ushort8v*)(vp + 8);
#pragma unroll
    for (int i = 0; i < 8; ++i) {
      oa[i] = fmaf(p, bf2f(v0[i]), oa[i]);
      oa[8 + i] = fmaf(p, bf2f(v1[i]), oa[8 + i]);
    }
  }
  ushort8v w0, w1;
#pragma unroll
  for (int i = 0; i < 8; ++i) { w0[i] = f2bf(oa[i]); w1[i] = f2bf(oa[8 + i]); }
  size_t orow = (size_t)r * 128 + h * DH_;
  *(ushort8v*)(o_s + orow) = w0;
  *(ushort8v*)(o_s + orow + 8) = w1;
}

// ---------------------------------------------------------------------------
// final_mfma: out(M,128) fp32 = o_t@Wt^T + o_s@Ws^T + (bt+bs). Two K=128
// phases sharing one 128x128 LDS double-tile; bf16 MFMA, fp32 accumulate.
// ---------------------------------------------------------------------------
__global__ __launch_bounds__(256) void final_mfma(
    const unsigned short* __restrict__ o_t, const unsigned short* __restrict__ o_s,
    const float* __restrict__ wt, const float* __restrict__ ws,
    const float* __restrict__ bt, const float* __restrict__ bs,
    float* __restrict__ out) {
  __shared__ unsigned short As[128 * 128];
  __shared__ unsigned short Bs[128 * 128];
  const int t = threadIdx.x;
  const int bm = blockIdx.x;
  const int wave = t >> 6, lane = t & 63;
  const int wm = (wave >> 1) * 64, wn = (wave & 1) * 64;
  const int lq = lane >> 4, l16 = lane & 15;
  floatx4 acc[4][4] = {};
#pragma unroll
  for (int p = 0; p < 2; ++p) {
    if (p) __syncthreads();
    const unsigned short* aSrc =
        (p ? o_s : o_t) + (size_t)bm * 128 * 128;
    const float* bSrc = p ? ws : wt;
#pragma unroll
    for (int it = 0; it < 8; ++it) {
      int gi = it * 256 + t;  // granule index, 16 granules/row
      int m = gi >> 4, g = gi & 15;
      int ps = m * 16 + (g ^ (m & 7));
      *(ushort8v*)(&As[ps * 8]) = *(const ushort8v*)(aSrc + m * 128 + g * 8);
      const float4* bp = (const float4*)(bSrc + m * 128 + g * 8);
      float4 b0 = bp[0], b1 = bp[1];
      ushort8v bb;
      bb[0] = f2bf(b0.x); bb[1] = f2bf(b0.y); bb[2] = f2bf(b0.z); bb[3] = f2bf(b0.w);
      bb[4] = f2bf(b1.x); bb[5] = f2bf(b1.y); bb[6] = f2bf(b1.z); bb[7] = f2bf(b1.w);
      *(ushort8v*)(&Bs[ps * 8]) = bb;
    }
    __syncthreads();
#pragma unroll
    for (int kk = 0; kk < 4; ++kk) {
      int g = kk * 4 + lq;
      short8 a[4], b[4];
#pragma unroll
      for (int i = 0; i < 4; ++i) {
        int ma = wm + i * 16 + l16;
        a[i] = *(const short8*)(&As[(ma * 16 + (g ^ (ma & 7))) * 8]);
        int nb = wn + i * 16 + l16;
        b[i] = *(const short8*)(&Bs[(nb * 16 + (g ^ (nb & 7))) * 8]);
      }
#pragma unroll
      for (int i = 0; i < 4; ++i)
#pragma unroll
        for (int j = 0; j < 4; ++j)
          acc[i][j] = __builtin_amdgcn_mfma_f32_16x16x32_bf16(a[i], b[j],
                                                              acc[i][j], 0, 0, 0);
    }
  }
  const size_t rowBase = (size_t)bm * 128 + wm;
  const int colBase = wn;
#pragma unroll
  for (int j = 0; j < 4; ++j) {
    int col = colBase + j * 16 + l16;
    float bb = bt[col] + bs[col];
#pragma unroll
    for (int i = 0; i < 4; ++i) {
#pragma unroll
      for (int r = 0; r < 4; ++r) {
        size_t row = rowBase + i * 16 + lq * 4 + r;
        out[row * 128 + col] = acc[i][j][r] + bb;
      }
    }
  }
}

extern "C" void kernel_launch(void* const* d_in, const int* in_sizes, int n_in,
                              void* d_out, int out_size, void* d_ws,
                              size_t ws_size, hipStream_t stream) {
  const float* x = (const float*)d_in[0];
  const int* route = (const int*)d_in[1];
  const float* t_in_w = (const float*)d_in[2];
  const float* t_in_b = (const float*)d_in[3];
  const float* t_out_w = (const float*)d_in[4];
  const float* t_out_b = (const float*)d_in[5];
  const float* s_in_w = (const float*)d_in[6];
  const float* s_in_b = (const float*)d_in[7];
  const float* s_out_w = (const float*)d_in[8];
  const float* s_out_b = (const float*)d_in[9];
  float* out = (float*)d_out;
  // workspace: qkv bf16 (98,304,000 B) | o_t bf16 (32,768,000 B) | o_s bf16
  unsigned short* qkv = (unsigned short*)d_ws;
  unsigned short* o_t = qkv + (size_t)M_ * 384;
  unsigned short* o_s = o_t + (size_t)M_ * 128;

  proj_mfma<<<(M_ / 128) * 3, 256, 0, stream>>>(x, t_in_w, t_in_b, qkv);
  tattn_kernel<<<B_ * N_, 256, 0, stream>>>(qkv, o_t);
  proj_mfma<<<(M_ / 128) * 3, 256, 0, stream>>>(x, s_in_w, s_in_b, qkv);
  sattn_kernel<<<M_ / 32, 256, 0, stream>>>(qkv, route, o_s);
  final_mfma<<<M_ / 128, 256, 0, stream>>>(o_t, o_s, t_out_w, s_out_w,
                                           t_out_b, s_out_b, out);
}

// Round 5
// 350.770 us; speedup vs baseline: 3.4091x; 1.1083x over previous
//
#include <hip/hip_runtime.h>
#include <math.h>

#define L_ 32
#define B_ 4
#define N_ 1000
#define D_ 128
#define H_ 8
#define DH_ 16
#define KN_ 8
#define M_ (L_ * B_ * N_)  // 128000 rows

typedef __attribute__((ext_vector_type(8))) short short8;
typedef __attribute__((ext_vector_type(8))) unsigned short ushort8v;
typedef __attribute__((ext_vector_type(4))) float floatx4;

static __device__ __forceinline__ unsigned short f2bf(float f) {
  union { float f; unsigned u; } v; v.f = f;
  unsigned r = v.u + 0x7fffu + ((v.u >> 16) & 1u);
  return (unsigned short)(r >> 16);
}
static __device__ __forceinline__ float bf2f(unsigned short s) {
  union { unsigned u; float f; } v; v.u = ((unsigned)s) << 16;
  return v.f;
}
// async global->LDS, 16B per lane; LDS dest is wave-uniform base + lane*16,
// so dest must be lane-contiguous (it is: we pass base + flat_id*16).
static __device__ __forceinline__ void gload_lds16(const unsigned short* g,
                                                   unsigned short* l) {
  __builtin_amdgcn_global_load_lds(
      (const __attribute__((address_space(1))) unsigned int*)g,
      (__attribute__((address_space(3))) unsigned int*)l, 16, 0, 0);
}

// ---------------------------------------------------------------------------
// prep: fp32 -> bf16 128x128 tile-images in LDS byte order (XOR-swizzled
// 16B granules: granule g of row m lands at m*16 + (g^(m&7))).
// Blocks 0..999: x tiles. 1000..1007: weight tiles
// (0-2 t_in, 3-5 s_in, 6 t_out, 7 s_out).
// ---------------------------------------------------------------------------
__global__ __launch_bounds__(256) void prep_kernel(
    const float* __restrict__ x, const float* __restrict__ wt_in,
    const float* __restrict__ ws_in, const float* __restrict__ wt_out,
    const float* __restrict__ ws_out, unsigned short* __restrict__ ximg,
    unsigned short* __restrict__ wimg) {
  const int bid = blockIdx.x, t = threadIdx.x;
  const float* src;
  unsigned short* dst;
  if (bid < 1000) {
    src = x + (size_t)bid * 16384;
    dst = ximg + (size_t)bid * 16384;
  } else {
    int w = bid - 1000;
    if (w < 3) src = wt_in + (size_t)w * 16384;
    else if (w < 6) src = ws_in + (size_t)(w - 3) * 16384;
    else if (w == 6) src = wt_out;
    else src = ws_out;
    dst = wimg + (size_t)w * 16384;
  }
#pragma unroll
  for (int it = 0; it < 8; ++it) {
    int gi = it * 256 + t;  // 0..2047
    int m = gi >> 4, g = gi & 15;
    const float4* sp = (const float4*)(src + m * 128 + g * 8);
    float4 a = sp[0], b = sp[1];
    ushort8v o;
    o[0] = f2bf(a.x); o[1] = f2bf(a.y); o[2] = f2bf(a.z); o[3] = f2bf(a.w);
    o[4] = f2bf(b.x); o[5] = f2bf(b.y); o[6] = f2bf(b.z); o[7] = f2bf(b.w);
    *(ushort8v*)(dst + (size_t)(m * 16 + (g ^ (m & 7))) * 8) = o;
  }
}

// ---------------------------------------------------------------------------
// proj_mfma: qkv(M,384) bf16 = x @ W^T + bias. Pure-DMA staging of
// pre-swizzled images; 128x128 tile; 4x4 grid of 16x16x32 bf16 MFMAs/wave.
// ---------------------------------------------------------------------------
__global__ __launch_bounds__(256) void proj_mfma(
    const unsigned short* __restrict__ ximg,
    const unsigned short* __restrict__ wimg, const float* __restrict__ bias,
    unsigned short* __restrict__ out) {
  __shared__ unsigned short As[128 * 128];
  __shared__ unsigned short Bs[128 * 128];
  const int t = threadIdx.x;
  const int bm = blockIdx.x / 3, bn = blockIdx.x % 3;
  const unsigned short* aSrc = ximg + (size_t)bm * 16384;
  const unsigned short* bSrc = wimg + (size_t)bn * 16384;
#pragma unroll
  for (int it = 0; it < 8; ++it) {
    int gi = it * 256 + t;
    gload_lds16(aSrc + (size_t)gi * 8, &As[gi * 8]);
    gload_lds16(bSrc + (size_t)gi * 8, &Bs[gi * 8]);
  }
  __syncthreads();
  const int wave = t >> 6, lane = t & 63;
  const int wm = (wave >> 1) * 64, wn = (wave & 1) * 64;
  const int lq = lane >> 4, l16 = lane & 15;
  floatx4 acc[4][4] = {};
#pragma unroll
  for (int kk = 0; kk < 4; ++kk) {
    int g = kk * 4 + lq;
    short8 a[4], b[4];
#pragma unroll
    for (int i = 0; i < 4; ++i) {
      int ma = wm + i * 16 + l16;
      a[i] = *(const short8*)(&As[(ma * 16 + (g ^ (ma & 7))) * 8]);
      int nb = wn + i * 16 + l16;
      b[i] = *(const short8*)(&Bs[(nb * 16 + (g ^ (nb & 7))) * 8]);
    }
#pragma unroll
    for (int i = 0; i < 4; ++i)
#pragma unroll
      for (int j = 0; j < 4; ++j)
        acc[i][j] = __builtin_amdgcn_mfma_f32_16x16x32_bf16(a[i], b[j],
                                                            acc[i][j], 0, 0, 0);
  }
  const size_t rowBase = (size_t)bm * 128 + wm;
  const int colBase = bn * 128 + wn;
#pragma unroll
  for (int j = 0; j < 4; ++j) {
    float bb = bias[colBase + j * 16 + l16];
#pragma unroll
    for (int i = 0; i < 4; ++i) {
#pragma unroll
      for (int r = 0; r < 4; ++r) {
        size_t row = rowBase + i * 16 + lq * 4 + r;
        out[row * 384 + colBase + j * 16 + l16] = f2bf(acc[i][j][r] + bb);
      }
    }
  }
}

// ---------------------------------------------------------------------------
// tattn: temporal attention, one block per (b,n). k/v DMA-staged to LDS
// (unpadded [32][256] -> lane-contiguous dest; compute reads are 8 distinct
// 16B segments x 8-lane broadcast, 2-way bank alias = free).
// Output written in swizzled tile-image layout for final_mfma DMA.
// ---------------------------------------------------------------------------
__global__ __launch_bounds__(256) void tattn_kernel(
    const unsigned short* __restrict__ qkv, unsigned short* __restrict__ oimg) {
  __shared__ unsigned short skv[32 * 256];  // row: k 0..127, v 128..255
  const int t = threadIdx.x;
  const int b = blockIdx.x / N_;
  const int n = blockIdx.x % N_;
#pragma unroll
  for (int it = 0; it < 4; ++it) {
    int e = it * 256 + t;
    int l = e >> 5, c8 = e & 31;  // 32 granules per row
    const unsigned short* g =
        qkv + ((size_t)(l * B_ + b) * N_ + n) * 384 + 128 + c8 * 8;
    gload_lds16(g, &skv[e * 8]);
  }
  __syncthreads();
  const int rl = t >> 3, h = t & 7;
  float q[16];
  {
    const unsigned short* qp =
        qkv + ((size_t)(rl * B_ + b) * N_ + n) * 384 + h * DH_;
    ushort8v q0 = *(const ushort8v*)qp;
    ushort8v q1 = *(const ushort8v*)(qp + 8);
#pragma unroll
    for (int i = 0; i < 8; ++i) { q[i] = bf2f(q0[i]); q[8 + i] = bf2f(q1[i]); }
  }
  float sc[32];
  float mx = -1e30f;
#pragma unroll
  for (int m = 0; m < 32; ++m) {
    const ushort8v k0 = *(const ushort8v*)(&skv[m * 256 + h * DH_]);
    const ushort8v k1 = *(const ushort8v*)(&skv[m * 256 + h * DH_ + 8]);
    float d = 0.f;
#pragma unroll
    for (int i = 0; i < 8; ++i) {
      d = fmaf(q[i], bf2f(k0[i]), d);
      d = fmaf(q[8 + i], bf2f(k1[i]), d);
    }
    d *= 0.25f;
    sc[m] = d;
    mx = fmaxf(mx, d);
  }
  float ssum = 0.f;
#pragma unroll
  for (int m = 0; m < 32; ++m) { sc[m] = __expf(sc[m] - mx); ssum += sc[m]; }
  float inv = 1.f / ssum;
  float oa[16];
#pragma unroll
  for (int i = 0; i < 16; ++i) oa[i] = 0.f;
#pragma unroll
  for (int m = 0; m < 32; ++m) {
    float p = sc[m] * inv;
    const ushort8v v0 = *(const ushort8v*)(&skv[m * 256 + 128 + h * DH_]);
    const ushort8v v1 = *(const ushort8v*)(&skv[m * 256 + 128 + h * DH_ + 8]);
#pragma unroll
    for (int i = 0; i < 8; ++i) {
      oa[i] = fmaf(p, bf2f(v0[i]), oa[i]);
      oa[8 + i] = fmaf(p, bf2f(v1[i]), oa[8 + i]);
    }
  }
  ushort8v w0, w1;
#pragma unroll
  for (int i = 0; i < 8; ++i) { w0[i] = f2bf(oa[i]); w1[i] = f2bf(oa[8 + i]); }
  const size_t r = (size_t)(rl * B_ + b) * N_ + n;
  const int m = (int)(r & 127);
  unsigned short* base = oimg + (r >> 7) * 16384;
  *(ushort8v*)(base + (size_t)(m * 16 + ((2 * h) ^ (m & 7))) * 8) = w0;
  *(ushort8v*)(base + (size_t)(m * 16 + ((2 * h + 1) ^ (m & 7))) * 8) = w1;
}

// ---------------------------------------------------------------------------
// sattn: spatial attention (K=8 gather of projected neighbors). One block
// per 32 rows. Output in swizzled tile-image layout.
// ---------------------------------------------------------------------------
__global__ __launch_bounds__(256) void sattn_kernel(
    const unsigned short* __restrict__ qkv, const int* __restrict__ route,
    unsigned short* __restrict__ oimg) {
  const int t = threadIdx.x;
  const int r0 = blockIdx.x * 32;
  const int rl = t >> 3, h = t & 7;
  const int r = r0 + rl;
  const int n = r % N_;
  const int lb = r / N_;  // l*B+b
  float q[16];
  {
    const unsigned short* qp = qkv + (size_t)r * 384 + h * DH_;
    ushort8v q0 = *(const ushort8v*)qp;
    ushort8v q1 = *(const ushort8v*)(qp + 8);
#pragma unroll
    for (int i = 0; i < 8; ++i) { q[i] = bf2f(q0[i]); q[8 + i] = bf2f(q1[i]); }
  }
  int nb[KN_];
#pragma unroll
  for (int kk = 0; kk < KN_; ++kk) nb[kk] = route[n * KN_ + kk];
  float sc[KN_];
  float mx = -1e30f;
#pragma unroll
  for (int kk = 0; kk < KN_; ++kk) {
    const unsigned short* kp =
        qkv + ((size_t)lb * N_ + nb[kk]) * 384 + 128 + h * DH_;
    ushort8v k0 = *(const ushort8v*)kp;
    ushort8v k1 = *(const ushort8v*)(kp + 8);
    float d = 0.f;
#pragma unroll
    for (int i = 0; i < 8; ++i) {
      d = fmaf(q[i], bf2f(k0[i]), d);
      d = fmaf(q[8 + i], bf2f(k1[i]), d);
    }
    d *= 0.25f;
    sc[kk] = d;
    mx = fmaxf(mx, d);
  }
  float ssum = 0.f;
#pragma unroll
  for (int kk = 0; kk < KN_; ++kk) { sc[kk] = __expf(sc[kk] - mx); ssum += sc[kk]; }
  float inv = 1.f / ssum;
  float oa[16];
#pragma unroll
  for (int i = 0; i < 16; ++i) oa[i] = 0.f;
#pragma unroll
  for (int kk = 0; kk < KN_; ++kk) {
    float p = sc[kk] * inv;
    const unsigned short* vp =
        qkv + ((size_t)lb * N_ + nb[kk]) * 384 + 256 + h * DH_;
    ushort8v v0 = *(const ushort8v*)vp;
    ushort8v v1 = *(const ushort8v*)(vp + 8);
#pragma unroll
    for (int i = 0; i < 8; ++i) {
      oa[i] = fmaf(p, bf2f(v0[i]), oa[i]);
      oa[8 + i] = fmaf(p, bf2f(v1[i]), oa[8 + i]);
    }
  }
  ushort8v w0, w1;
#pragma unroll
  for (int i = 0; i < 8; ++i) { w0[i] = f2bf(oa[i]); w1[i] = f2bf(oa[8 + i]); }
  const int m = r & 127;
  unsigned short* base = oimg + (size_t)(r >> 7) * 16384;
  *(ushort8v*)(base + (size_t)(m * 16 + ((2 * h) ^ (m & 7))) * 8) = w0;
  *(ushort8v*)(base + (size_t)(m * 16 + ((2 * h + 1) ^ (m & 7))) * 8) = w1;
}

// ---------------------------------------------------------------------------
// final_mfma: out(M,128) fp32 = o_t@Wt^T + o_s@Ws^T + (bt+bs).
// Two K=128 phases, both sides DMA-staged from pre-swizzled images.
// ---------------------------------------------------------------------------
__global__ __launch_bounds__(256) void final_mfma(
    const unsigned short* __restrict__ otimg,
    const unsigned short* __restrict__ osimg,
    const unsigned short* __restrict__ wtimg,
    const unsigned short* __restrict__ wsimg, const float* __restrict__ bt,
    const float* __restrict__ bs, float* __restrict__ out) {
  __shared__ unsigned short As[128 * 128];
  __shared__ unsigned short Bs[128 * 128];
  const int t = threadIdx.x;
  const int bm = blockIdx.x;
  const int wave = t >> 6, lane = t & 63;
  const int wm = (wave >> 1) * 64, wn = (wave & 1) * 64;
  const int lq = lane >> 4, l16 = lane & 15;
  floatx4 acc[4][4] = {};
#pragma unroll
  for (int p = 0; p < 2; ++p) {
    if (p) __syncthreads();
    const unsigned short* aSrc = (p ? osimg : otimg) + (size_t)bm * 16384;
    const unsigned short* bSrc = p ? wsimg : wtimg;
#pragma unroll
    for (int it = 0; it < 8; ++it) {
      int gi = it * 256 + t;
      gload_lds16(aSrc + (size_t)gi * 8, &As[gi * 8]);
      gload_lds16(bSrc + (size_t)gi * 8, &Bs[gi * 8]);
    }
    __syncthreads();
#pragma unroll
    for (int kk = 0; kk < 4; ++kk) {
      int g = kk * 4 + lq;
      short8 a[4], b[4];
#pragma unroll
      for (int i = 0; i < 4; ++i) {
        int ma = wm + i * 16 + l16;
        a[i] = *(const short8*)(&As[(ma * 16 + (g ^ (ma & 7))) * 8]);
        int nb = wn + i * 16 + l16;
        b[i] = *(const short8*)(&Bs[(nb * 16 + (g ^ (nb & 7))) * 8]);
      }
#pragma unroll
      for (int i = 0; i < 4; ++i)
#pragma unroll
        for (int j = 0; j < 4; ++j)
          acc[i][j] = __builtin_amdgcn_mfma_f32_16x16x32_bf16(a[i], b[j],
                                                              acc[i][j], 0, 0, 0);
    }
  }
  const size_t rowBase = (size_t)bm * 128 + wm;
#pragma unroll
  for (int j = 0; j < 4; ++j) {
    int col = wn + j * 16 + l16;
    float bb = bt[col] + bs[col];
#pragma unroll
    for (int i = 0; i < 4; ++i) {
#pragma unroll
      for (int r = 0; r < 4; ++r) {
        size_t row = rowBase + i * 16 + lq * 4 + r;
        out[row * 128 + col] = acc[i][j][r] + bb;
      }
    }
  }
}

extern "C" void kernel_launch(void* const* d_in, const int* in_sizes, int n_in,
                              void* d_out, int out_size, void* d_ws,
                              size_t ws_size, hipStream_t stream) {
  const float* x = (const float*)d_in[0];
  const int* route = (const int*)d_in[1];
  const float* t_in_w = (const float*)d_in[2];
  const float* t_in_b = (const float*)d_in[3];
  const float* t_out_w = (const float*)d_in[4];
  const float* t_out_b = (const float*)d_in[5];
  const float* s_in_w = (const float*)d_in[6];
  const float* s_in_b = (const float*)d_in[7];
  const float* s_out_w = (const float*)d_in[8];
  const float* s_out_b = (const float*)d_in[9];
  float* out = (float*)d_out;
  // ws (ushorts): ximg [M*128] | qkv [M*384] | o_t img [M*128] | wimg [8*16384]
  // o_s img aliases ximg (dead after proj_s reads it). Total 164.1 MB.
  unsigned short* ximg = (unsigned short*)d_ws;
  unsigned short* qkv = ximg + (size_t)M_ * 128;
  unsigned short* o_t = qkv + (size_t)M_ * 384;
  unsigned short* wimg = o_t + (size_t)M_ * 128;
  unsigned short* o_s = ximg;  // alias

  prep_kernel<<<1008, 256, 0, stream>>>(x, t_in_w, s_in_w, t_out_w, s_out_w,
                                        ximg, wimg);
  proj_mfma<<<(M_ / 128) * 3, 256, 0, stream>>>(ximg, wimg, t_in_b, qkv);
  tattn_kernel<<<B_ * N_, 256, 0, stream>>>(qkv, o_t);
  proj_mfma<<<(M_ / 128) * 3, 256, 0, stream>>>(ximg, wimg + 3 * 16384,
                                                s_in_b, qkv);
  sattn_kernel<<<M_ / 32, 256, 0, stream>>>(qkv, route, o_s);
  final_mfma<<<M_ / 128, 256, 0, stream>>>(o_t, o_s, wimg + 6 * 16384,
                                           wimg + 7 * 16384, t_out_b, s_out_b,
                                           out);
}

// Round 6
// 331.794 us; speedup vs baseline: 3.6041x; 1.0572x over previous
//
#include <hip/hip_runtime.h>
#include <math.h>

#define L_ 32
#define B_ 4
#define N_ 1000
#define D_ 128
#define H_ 8
#define DH_ 16
#define KN_ 8
#define M_ (L_ * B_ * N_)  // 128000 rows

typedef __attribute__((ext_vector_type(8))) short short8;
typedef __attribute__((ext_vector_type(8))) unsigned short ushort8v;
typedef __attribute__((ext_vector_type(4))) float floatx4;

static __device__ __forceinline__ unsigned short f2bf(float f) {
  union { float f; unsigned u; } v; v.f = f;
  unsigned r = v.u + 0x7fffu + ((v.u >> 16) & 1u);
  return (unsigned short)(r >> 16);
}
static __device__ __forceinline__ float bf2f(unsigned short s) {
  union { unsigned u; float f; } v; v.u = ((unsigned)s) << 16;
  return v.f;
}
// async global->LDS, 16B per lane; LDS dest is wave-uniform base + lane*16.
static __device__ __forceinline__ void gload_lds16(const unsigned short* g,
                                                   unsigned short* l) {
  __builtin_amdgcn_global_load_lds(
      (const __attribute__((address_space(1))) unsigned int*)g,
      (__attribute__((address_space(3))) unsigned int*)l, 16, 0, 0);
}

// ---------------------------------------------------------------------------
// prep: fp32 -> bf16 128x128 tile-images in LDS byte order (XOR-swizzled
// 16B granules: granule g of row m lands at m*16 + (g^(m&7))).
// Blocks 0..999: x tiles. 1000..1007: weight tiles
// (0-2 t_in, 3-5 s_in, 6 t_out, 7 s_out).
// ---------------------------------------------------------------------------
__global__ __launch_bounds__(256) void prep_kernel(
    const float* __restrict__ x, const float* __restrict__ wt_in,
    const float* __restrict__ ws_in, const float* __restrict__ wt_out,
    const float* __restrict__ ws_out, unsigned short* __restrict__ ximg,
    unsigned short* __restrict__ wimg) {
  const int bid = blockIdx.x, t = threadIdx.x;
  const float* src;
  unsigned short* dst;
  if (bid < 1000) {
    src = x + (size_t)bid * 16384;
    dst = ximg + (size_t)bid * 16384;
  } else {
    int w = bid - 1000;
    if (w < 3) src = wt_in + (size_t)w * 16384;
    else if (w < 6) src = ws_in + (size_t)(w - 3) * 16384;
    else if (w == 6) src = wt_out;
    else src = ws_out;
    dst = wimg + (size_t)w * 16384;
  }
#pragma unroll
  for (int it = 0; it < 8; ++it) {
    int gi = it * 256 + t;  // 0..2047
    int m = gi >> 4, g = gi & 15;
    const float4* sp = (const float4*)(src + m * 128 + g * 8);
    float4 a = sp[0], b = sp[1];
    ushort8v o;
    o[0] = f2bf(a.x); o[1] = f2bf(a.y); o[2] = f2bf(a.z); o[3] = f2bf(a.w);
    o[4] = f2bf(b.x); o[5] = f2bf(b.y); o[6] = f2bf(b.z); o[7] = f2bf(b.w);
    *(ushort8v*)(dst + (size_t)(m * 16 + (g ^ (m & 7))) * 8) = o;
  }
}

// ---------------------------------------------------------------------------
// proj_mfma: qkv(M,384) bf16 = x @ W^T + bias. Pure-DMA staging of
// pre-swizzled images; 128x128 tile; 4x4 grid of 16x16x32 bf16 MFMAs/wave.
// ---------------------------------------------------------------------------
__global__ __launch_bounds__(256) void proj_mfma(
    const unsigned short* __restrict__ ximg,
    const unsigned short* __restrict__ wimg, const float* __restrict__ bias,
    unsigned short* __restrict__ out) {
  __shared__ unsigned short As[128 * 128];
  __shared__ unsigned short Bs[128 * 128];
  const int t = threadIdx.x;
  const int bm = blockIdx.x / 3, bn = blockIdx.x % 3;
  const unsigned short* aSrc = ximg + (size_t)bm * 16384;
  const unsigned short* bSrc = wimg + (size_t)bn * 16384;
#pragma unroll
  for (int it = 0; it < 8; ++it) {
    int gi = it * 256 + t;
    gload_lds16(aSrc + (size_t)gi * 8, &As[gi * 8]);
    gload_lds16(bSrc + (size_t)gi * 8, &Bs[gi * 8]);
  }
  __syncthreads();
  const int wave = t >> 6, lane = t & 63;
  const int wm = (wave >> 1) * 64, wn = (wave & 1) * 64;
  const int lq = lane >> 4, l16 = lane & 15;
  floatx4 acc[4][4] = {};
#pragma unroll
  for (int kk = 0; kk < 4; ++kk) {
    int g = kk * 4 + lq;
    short8 a[4], b[4];
#pragma unroll
    for (int i = 0; i < 4; ++i) {
      int ma = wm + i * 16 + l16;
      a[i] = *(const short8*)(&As[(ma * 16 + (g ^ (ma & 7))) * 8]);
      int nb = wn + i * 16 + l16;
      b[i] = *(const short8*)(&Bs[(nb * 16 + (g ^ (nb & 7))) * 8]);
    }
#pragma unroll
    for (int i = 0; i < 4; ++i)
#pragma unroll
      for (int j = 0; j < 4; ++j)
        acc[i][j] = __builtin_amdgcn_mfma_f32_16x16x32_bf16(a[i], b[j],
                                                            acc[i][j], 0, 0, 0);
  }
  const size_t rowBase = (size_t)bm * 128 + wm;
  const int colBase = bn * 128 + wn;
#pragma unroll
  for (int j = 0; j < 4; ++j) {
    float bb = bias[colBase + j * 16 + l16];
#pragma unroll
    for (int i = 0; i < 4; ++i) {
#pragma unroll
      for (int r = 0; r < 4; ++r) {
        size_t row = rowBase + i * 16 + lq * 4 + r;
        out[row * 384 + colBase + j * 16 + l16] = f2bf(acc[i][j][r] + bb);
      }
    }
  }
}

// ---------------------------------------------------------------------------
// tattn: temporal attention, one block per (b,n).
// R6: k/v converted bf16->fp32 ONCE at staging (was 32x redundant in-loop).
// LDS layout: per row m (stride 320 floats): k segs h*20 (16 used + 4 pad),
// v segs 160 + h*20. Segment starts hit banks {0,20,8,28,16,4,24,12} -> the
// 8 distinct addresses per read instr are conflict-free; 8 rl-lanes per h
// are same-address broadcasts (free). Output in swizzled tile-image layout.
// ---------------------------------------------------------------------------
__global__ __launch_bounds__(256) void tattn_kernel(
    const unsigned short* __restrict__ qkv, unsigned short* __restrict__ oimg) {
  __shared__ float skv[32 * 320];  // 40 KB
  const int t = threadIdx.x;
  const int b = blockIdx.x / N_;
  const int n = blockIdx.x % N_;
#pragma unroll
  for (int it = 0; it < 4; ++it) {
    int e = it * 256 + t;
    int l = e >> 5, c8 = e & 31;  // granule c8 of row l (k: 0-15, v: 16-31)
    const unsigned short* g =
        qkv + ((size_t)(l * B_ + b) * N_ + n) * 384 + 128 + c8 * 8;
    ushort8v u = *(const ushort8v*)g;
    int seg = (c8 < 16) ? ((c8 >> 1) * 20 + (c8 & 1) * 8)
                        : (160 + ((c8 - 16) >> 1) * 20 + (c8 & 1) * 8);
    float* d = &skv[l * 320 + seg];
#pragma unroll
    for (int i = 0; i < 8; ++i) d[i] = bf2f(u[i]);
  }
  __syncthreads();
  const int rl = t >> 3, h = t & 7;
  float q[16];
  {
    const unsigned short* qp =
        qkv + ((size_t)(rl * B_ + b) * N_ + n) * 384 + h * DH_;
    ushort8v q0 = *(const ushort8v*)qp;
    ushort8v q1 = *(const ushort8v*)(qp + 8);
#pragma unroll
    for (int i = 0; i < 8; ++i) { q[i] = bf2f(q0[i]); q[8 + i] = bf2f(q1[i]); }
  }
  float sc[32];
  float mx = -1e30f;
#pragma unroll
  for (int m = 0; m < 32; ++m) {
    const float4* kp = (const float4*)(&skv[m * 320 + h * 20]);
    float4 k0 = kp[0], k1 = kp[1], k2 = kp[2], k3 = kp[3];
    float d = 0.f;
    d = fmaf(q[0], k0.x, d);  d = fmaf(q[1], k0.y, d);
    d = fmaf(q[2], k0.z, d);  d = fmaf(q[3], k0.w, d);
    d = fmaf(q[4], k1.x, d);  d = fmaf(q[5], k1.y, d);
    d = fmaf(q[6], k1.z, d);  d = fmaf(q[7], k1.w, d);
    d = fmaf(q[8], k2.x, d);  d = fmaf(q[9], k2.y, d);
    d = fmaf(q[10], k2.z, d); d = fmaf(q[11], k2.w, d);
    d = fmaf(q[12], k3.x, d); d = fmaf(q[13], k3.y, d);
    d = fmaf(q[14], k3.z, d); d = fmaf(q[15], k3.w, d);
    d *= 0.25f;
    sc[m] = d;
    mx = fmaxf(mx, d);
  }
  float ssum = 0.f;
#pragma unroll
  for (int m = 0; m < 32; ++m) { sc[m] = __expf(sc[m] - mx); ssum += sc[m]; }
  float inv = 1.f / ssum;
  float oa[16];
#pragma unroll
  for (int i = 0; i < 16; ++i) oa[i] = 0.f;
#pragma unroll
  for (int m = 0; m < 32; ++m) {
    float p = sc[m] * inv;
    const float4* vp = (const float4*)(&skv[m * 320 + 160 + h * 20]);
    float4 v0 = vp[0], v1 = vp[1], v2 = vp[2], v3 = vp[3];
    oa[0] = fmaf(p, v0.x, oa[0]);   oa[1] = fmaf(p, v0.y, oa[1]);
    oa[2] = fmaf(p, v0.z, oa[2]);   oa[3] = fmaf(p, v0.w, oa[3]);
    oa[4] = fmaf(p, v1.x, oa[4]);   oa[5] = fmaf(p, v1.y, oa[5]);
    oa[6] = fmaf(p, v1.z, oa[6]);   oa[7] = fmaf(p, v1.w, oa[7]);
    oa[8] = fmaf(p, v2.x, oa[8]);   oa[9] = fmaf(p, v2.y, oa[9]);
    oa[10] = fmaf(p, v2.z, oa[10]); oa[11] = fmaf(p, v2.w, oa[11]);
    oa[12] = fmaf(p, v3.x, oa[12]); oa[13] = fmaf(p, v3.y, oa[13]);
    oa[14] = fmaf(p, v3.z, oa[14]); oa[15] = fmaf(p, v3.w, oa[15]);
  }
  ushort8v w0, w1;
#pragma unroll
  for (int i = 0; i < 8; ++i) { w0[i] = f2bf(oa[i]); w1[i] = f2bf(oa[8 + i]); }
  const size_t r = (size_t)(rl * B_ + b) * N_ + n;
  const int m = (int)(r & 127);
  unsigned short* base = oimg + (r >> 7) * 16384;
  *(ushort8v*)(base + (size_t)(m * 16 + ((2 * h) ^ (m & 7))) * 8) = w0;
  *(ushort8v*)(base + (size_t)(m * 16 + ((2 * h + 1) ^ (m & 7))) * 8) = w1;
}

// ---------------------------------------------------------------------------
// sattn: spatial attention (K=8 gather of projected neighbors). One block
// per 32 rows. Output in swizzled tile-image layout.
// ---------------------------------------------------------------------------
__global__ __launch_bounds__(256) void sattn_kernel(
    const unsigned short* __restrict__ qkv, const int* __restrict__ route,
    unsigned short* __restrict__ oimg) {
  const int t = threadIdx.x;
  const int r0 = blockIdx.x * 32;
  const int rl = t >> 3, h = t & 7;
  const int r = r0 + rl;
  const int n = r % N_;
  const int lb = r / N_;  // l*B+b
  float q[16];
  {
    const unsigned short* qp = qkv + (size_t)r * 384 + h * DH_;
    ushort8v q0 = *(const ushort8v*)qp;
    ushort8v q1 = *(const ushort8v*)(qp + 8);
#pragma unroll
    for (int i = 0; i < 8; ++i) { q[i] = bf2f(q0[i]); q[8 + i] = bf2f(q1[i]); }
  }
  int nb[KN_];
#pragma unroll
  for (int kk = 0; kk < KN_; ++kk) nb[kk] = route[n * KN_ + kk];
  float sc[KN_];
  float mx = -1e30f;
#pragma unroll
  for (int kk = 0; kk < KN_; ++kk) {
    const unsigned short* kp =
        qkv + ((size_t)lb * N_ + nb[kk]) * 384 + 128 + h * DH_;
    ushort8v k0 = *(const ushort8v*)kp;
    ushort8v k1 = *(const ushort8v*)(kp + 8);
    float d = 0.f;
#pragma unroll
    for (int i = 0; i < 8; ++i) {
      d = fmaf(q[i], bf2f(k0[i]), d);
      d = fmaf(q[8 + i], bf2f(k1[i]), d);
    }
    d *= 0.25f;
    sc[kk] = d;
    mx = fmaxf(mx, d);
  }
  float ssum = 0.f;
#pragma unroll
  for (int kk = 0; kk < KN_; ++kk) { sc[kk] = __expf(sc[kk] - mx); ssum += sc[kk]; }
  float inv = 1.f / ssum;
  float oa[16];
#pragma unroll
  for (int i = 0; i < 16; ++i) oa[i] = 0.f;
#pragma unroll
  for (int kk = 0; kk < KN_; ++kk) {
    float p = sc[kk] * inv;
    const unsigned short* vp =
        qkv + ((size_t)lb * N_ + nb[kk]) * 384 + 256 + h * DH_;
    ushort8v v0 = *(const ushort8v*)vp;
    ushort8v v1 = *(const ushort8v*)(vp + 8);
#pragma unroll
    for (int i = 0; i < 8; ++i) {
      oa[i] = fmaf(p, bf2f(v0[i]), oa[i]);
      oa[8 + i] = fmaf(p, bf2f(v1[i]), oa[8 + i]);
    }
  }
  ushort8v w0, w1;
#pragma unroll
  for (int i = 0; i < 8; ++i) { w0[i] = f2bf(oa[i]); w1[i] = f2bf(oa[8 + i]); }
  const int m = r & 127;
  unsigned short* base = oimg + (size_t)(r >> 7) * 16384;
  *(ushort8v*)(base + (size_t)(m * 16 + ((2 * h) ^ (m & 7))) * 8) = w0;
  *(ushort8v*)(base + (size_t)(m * 16 + ((2 * h + 1) ^ (m & 7))) * 8) = w1;
}

// ---------------------------------------------------------------------------
// final_mfma: out(M,128) fp32 = o_t@Wt^T + o_s@Ws^T + (bt+bs).
// Two K=128 phases, both sides DMA-staged from pre-swizzled images.
// ---------------------------------------------------------------------------
__global__ __launch_bounds__(256) void final_mfma(
    const unsigned short* __restrict__ otimg,
    const unsigned short* __restrict__ osimg,
    const unsigned short* __restrict__ wtimg,
    const unsigned short* __restrict__ wsimg, const float* __restrict__ bt,
    const float* __restrict__ bs, float* __restrict__ out) {
  __shared__ unsigned short As[128 * 128];
  __shared__ unsigned short Bs[128 * 128];
  const int t = threadIdx.x;
  const int bm = blockIdx.x;
  const int wave = t >> 6, lane = t & 63;
  const int wm = (wave >> 1) * 64, wn = (wave & 1) * 64;
  const int lq = lane >> 4, l16 = lane & 15;
  floatx4 acc[4][4] = {};
#pragma unroll
  for (int p = 0; p < 2; ++p) {
    if (p) __syncthreads();
    const unsigned short* aSrc = (p ? osimg : otimg) + (size_t)bm * 16384;
    const unsigned short* bSrc = p ? wsimg : wtimg;
#pragma unroll
    for (int it = 0; it < 8; ++it) {
      int gi = it * 256 + t;
      gload_lds16(aSrc + (size_t)gi * 8, &As[gi * 8]);
      gload_lds16(bSrc + (size_t)gi * 8, &Bs[gi * 8]);
    }
    __syncthreads();
#pragma unroll
    for (int kk = 0; kk < 4; ++kk) {
      int g = kk * 4 + lq;
      short8 a[4], b[4];
#pragma unroll
      for (int i = 0; i < 4; ++i) {
        int ma = wm + i * 16 + l16;
        a[i] = *(const short8*)(&As[(ma * 16 + (g ^ (ma & 7))) * 8]);
        int nb = wn + i * 16 + l16;
        b[i] = *(const short8*)(&Bs[(nb * 16 + (g ^ (nb & 7))) * 8]);
      }
#pragma unroll
      for (int i = 0; i < 4; ++i)
#pragma unroll
        for (int j = 0; j < 4; ++j)
          acc[i][j] = __builtin_amdgcn_mfma_f32_16x16x32_bf16(a[i], b[j],
                                                              acc[i][j], 0, 0, 0);
    }
  }
  const size_t rowBase = (size_t)bm * 128 + wm;
#pragma unroll
  for (int j = 0; j < 4; ++j) {
    int col = wn + j * 16 + l16;
    float bb = bt[col] + bs[col];
#pragma unroll
    for (int i = 0; i < 4; ++i) {
#pragma unroll
      for (int r = 0; r < 4; ++r) {
        size_t row = rowBase + i * 16 + lq * 4 + r;
        out[row * 128 + col] = acc[i][j][r] + bb;
      }
    }
  }
}

extern "C" void kernel_launch(void* const* d_in, const int* in_sizes, int n_in,
                              void* d_out, int out_size, void* d_ws,
                              size_t ws_size, hipStream_t stream) {
  const float* x = (const float*)d_in[0];
  const int* route = (const int*)d_in[1];
  const float* t_in_w = (const float*)d_in[2];
  const float* t_in_b = (const float*)d_in[3];
  const float* t_out_w = (const float*)d_in[4];
  const float* t_out_b = (const float*)d_in[5];
  const float* s_in_w = (const float*)d_in[6];
  const float* s_in_b = (const float*)d_in[7];
  const float* s_out_w = (const float*)d_in[8];
  const float* s_out_b = (const float*)d_in[9];
  float* out = (float*)d_out;
  // ws (ushorts): ximg [M*128] | qkv [M*384] | o_t img [M*128] | wimg [8*16384]
  // o_s img aliases ximg (dead after proj_s reads it). Total 164.1 MB.
  unsigned short* ximg = (unsigned short*)d_ws;
  unsigned short* qkv = ximg + (size_t)M_ * 128;
  unsigned short* o_t = qkv + (size_t)M_ * 384;
  unsigned short* wimg = o_t + (size_t)M_ * 128;
  unsigned short* o_s = ximg;  // alias

  prep_kernel<<<1008, 256, 0, stream>>>(x, t_in_w, s_in_w, t_out_w, s_out_w,
                                        ximg, wimg);
  proj_mfma<<<(M_ / 128) * 3, 256, 0, stream>>>(ximg, wimg, t_in_b, qkv);
  tattn_kernel<<<B_ * N_, 256, 0, stream>>>(qkv, o_t);
  proj_mfma<<<(M_ / 128) * 3, 256, 0, stream>>>(ximg, wimg + 3 * 16384,
                                                s_in_b, qkv);
  sattn_kernel<<<M_ / 32, 256, 0, stream>>>(qkv, route, o_s);
  final_mfma<<<M_ / 128, 256, 0, stream>>>(o_t, o_s, wimg + 6 * 16384,
                                           wimg + 7 * 16384, t_out_b, s_out_b,
                                           out);
}

// Round 7
// 305.288 us; speedup vs baseline: 3.9170x; 1.0868x over previous
//
#include <hip/hip_runtime.h>
#include <math.h>

#define L_ 32
#define B_ 4
#define N_ 1000
#define D_ 128
#define H_ 8
#define DH_ 16
#define KN_ 8
#define M_ (L_ * B_ * N_)  // 128000 rows

typedef __attribute__((ext_vector_type(8))) short short8;
typedef __attribute__((ext_vector_type(8))) unsigned short ushort8v;
typedef __attribute__((ext_vector_type(4))) float floatx4;

static __device__ __forceinline__ unsigned short f2bf(float f) {
  union { float f; unsigned u; } v; v.f = f;
  unsigned r = v.u + 0x7fffu + ((v.u >> 16) & 1u);
  return (unsigned short)(r >> 16);
}
static __device__ __forceinline__ float bf2f(unsigned short s) {
  union { unsigned u; float f; } v; v.u = ((unsigned)s) << 16;
  return v.f;
}
// async global->LDS, 16B per lane; LDS dest is wave-uniform base + lane*16.
static __device__ __forceinline__ void gload_lds16(const unsigned short* g,
                                                   unsigned short* l) {
  __builtin_amdgcn_global_load_lds(
      (const __attribute__((address_space(1))) unsigned int*)g,
      (__attribute__((address_space(3))) unsigned int*)l, 16, 0, 0);
}

// ---------------------------------------------------------------------------
// prep: fp32 -> bf16 128x128 tile-images in LDS byte order (XOR-swizzled
// 16B granules: granule g of row m lands at m*16 + (g^(m&7))).
// Blocks 0..999: x tiles. 1000..1007: weight tiles
// (0-2 t_in, 3-5 s_in, 6 t_out, 7 s_out).
// ---------------------------------------------------------------------------
__global__ __launch_bounds__(256) void prep_kernel(
    const float* __restrict__ x, const float* __restrict__ wt_in,
    const float* __restrict__ ws_in, const float* __restrict__ wt_out,
    const float* __restrict__ ws_out, unsigned short* __restrict__ ximg,
    unsigned short* __restrict__ wimg) {
  const int bid = blockIdx.x, t = threadIdx.x;
  const float* src;
  unsigned short* dst;
  if (bid < 1000) {
    src = x + (size_t)bid * 16384;
    dst = ximg + (size_t)bid * 16384;
  } else {
    int w = bid - 1000;
    if (w < 3) src = wt_in + (size_t)w * 16384;
    else if (w < 6) src = ws_in + (size_t)(w - 3) * 16384;
    else if (w == 6) src = wt_out;
    else src = ws_out;
    dst = wimg + (size_t)w * 16384;
  }
#pragma unroll
  for (int it = 0; it < 8; ++it) {
    int gi = it * 256 + t;  // 0..2047
    int m = gi >> 4, g = gi & 15;
    const float4* sp = (const float4*)(src + m * 128 + g * 8);
    float4 a = sp[0], b = sp[1];
    ushort8v o;
    o[0] = f2bf(a.x); o[1] = f2bf(a.y); o[2] = f2bf(a.z); o[3] = f2bf(a.w);
    o[4] = f2bf(b.x); o[5] = f2bf(b.y); o[6] = f2bf(b.z); o[7] = f2bf(b.w);
    *(ushort8v*)(dst + (size_t)(m * 16 + (g ^ (m & 7))) * 8) = o;
  }
}

// ---------------------------------------------------------------------------
// proj_mfma: qkv(M,384) bf16 = x @ W^T + bias. Pure-DMA staging of
// pre-swizzled images; 128x128 tile; 4x4 grid of 16x16x32 bf16 MFMAs/wave.
// ---------------------------------------------------------------------------
__global__ __launch_bounds__(256) void proj_mfma(
    const unsigned short* __restrict__ ximg,
    const unsigned short* __restrict__ wimg, const float* __restrict__ bias,
    unsigned short* __restrict__ out) {
  __shared__ unsigned short As[128 * 128];
  __shared__ unsigned short Bs[128 * 128];
  const int t = threadIdx.x;
  const int bm = blockIdx.x / 3, bn = blockIdx.x % 3;
  const unsigned short* aSrc = ximg + (size_t)bm * 16384;
  const unsigned short* bSrc = wimg + (size_t)bn * 16384;
#pragma unroll
  for (int it = 0; it < 8; ++it) {
    int gi = it * 256 + t;
    gload_lds16(aSrc + (size_t)gi * 8, &As[gi * 8]);
    gload_lds16(bSrc + (size_t)gi * 8, &Bs[gi * 8]);
  }
  __syncthreads();
  const int wave = t >> 6, lane = t & 63;
  const int wm = (wave >> 1) * 64, wn = (wave & 1) * 64;
  const int lq = lane >> 4, l16 = lane & 15;
  floatx4 acc[4][4] = {};
#pragma unroll
  for (int kk = 0; kk < 4; ++kk) {
    int g = kk * 4 + lq;
    short8 a[4], b[4];
#pragma unroll
    for (int i = 0; i < 4; ++i) {
      int ma = wm + i * 16 + l16;
      a[i] = *(const short8*)(&As[(ma * 16 + (g ^ (ma & 7))) * 8]);
      int nb = wn + i * 16 + l16;
      b[i] = *(const short8*)(&Bs[(nb * 16 + (g ^ (nb & 7))) * 8]);
    }
#pragma unroll
    for (int i = 0; i < 4; ++i)
#pragma unroll
      for (int j = 0; j < 4; ++j)
        acc[i][j] = __builtin_amdgcn_mfma_f32_16x16x32_bf16(a[i], b[j],
                                                            acc[i][j], 0, 0, 0);
  }
  const size_t rowBase = (size_t)bm * 128 + wm;
  const int colBase = bn * 128 + wn;
#pragma unroll
  for (int j = 0; j < 4; ++j) {
    float bb = bias[colBase + j * 16 + l16];
#pragma unroll
    for (int i = 0; i < 4; ++i) {
#pragma unroll
      for (int r = 0; r < 4; ++r) {
        size_t row = rowBase + i * 16 + lq * 4 + r;
        out[row * 384 + colBase + j * 16 + l16] = f2bf(acc[i][j][r] + bb);
      }
    }
  }
}

// ---------------------------------------------------------------------------
// tattn: temporal attention, one block per (b,n). k/v converted to fp32 once
// at staging; bank-spread 20-float segments (see R6 notes).
// ---------------------------------------------------------------------------
__global__ __launch_bounds__(256) void tattn_kernel(
    const unsigned short* __restrict__ qkv, unsigned short* __restrict__ oimg) {
  __shared__ float skv[32 * 320];  // 40 KB
  const int t = threadIdx.x;
  const int b = blockIdx.x / N_;
  const int n = blockIdx.x % N_;
#pragma unroll
  for (int it = 0; it < 4; ++it) {
    int e = it * 256 + t;
    int l = e >> 5, c8 = e & 31;  // granule c8 of row l (k: 0-15, v: 16-31)
    const unsigned short* g =
        qkv + ((size_t)(l * B_ + b) * N_ + n) * 384 + 128 + c8 * 8;
    ushort8v u = *(const ushort8v*)g;
    int seg = (c8 < 16) ? ((c8 >> 1) * 20 + (c8 & 1) * 8)
                        : (160 + ((c8 - 16) >> 1) * 20 + (c8 & 1) * 8);
    float* d = &skv[l * 320 + seg];
#pragma unroll
    for (int i = 0; i < 8; ++i) d[i] = bf2f(u[i]);
  }
  __syncthreads();
  const int rl = t >> 3, h = t & 7;
  float q[16];
  {
    const unsigned short* qp =
        qkv + ((size_t)(rl * B_ + b) * N_ + n) * 384 + h * DH_;
    ushort8v q0 = *(const ushort8v*)qp;
    ushort8v q1 = *(const ushort8v*)(qp + 8);
#pragma unroll
    for (int i = 0; i < 8; ++i) { q[i] = bf2f(q0[i]); q[8 + i] = bf2f(q1[i]); }
  }
  float sc[32];
  float mx = -1e30f;
#pragma unroll
  for (int m = 0; m < 32; ++m) {
    const float4* kp = (const float4*)(&skv[m * 320 + h * 20]);
    float4 k0 = kp[0], k1 = kp[1], k2 = kp[2], k3 = kp[3];
    float d = 0.f;
    d = fmaf(q[0], k0.x, d);  d = fmaf(q[1], k0.y, d);
    d = fmaf(q[2], k0.z, d);  d = fmaf(q[3], k0.w, d);
    d = fmaf(q[4], k1.x, d);  d = fmaf(q[5], k1.y, d);
    d = fmaf(q[6], k1.z, d);  d = fmaf(q[7], k1.w, d);
    d = fmaf(q[8], k2.x, d);  d = fmaf(q[9], k2.y, d);
    d = fmaf(q[10], k2.z, d); d = fmaf(q[11], k2.w, d);
    d = fmaf(q[12], k3.x, d); d = fmaf(q[13], k3.y, d);
    d = fmaf(q[14], k3.z, d); d = fmaf(q[15], k3.w, d);
    d *= 0.25f;
    sc[m] = d;
    mx = fmaxf(mx, d);
  }
  float ssum = 0.f;
#pragma unroll
  for (int m = 0; m < 32; ++m) { sc[m] = __expf(sc[m] - mx); ssum += sc[m]; }
  float inv = 1.f / ssum;
  float oa[16];
#pragma unroll
  for (int i = 0; i < 16; ++i) oa[i] = 0.f;
#pragma unroll
  for (int m = 0; m < 32; ++m) {
    float p = sc[m] * inv;
    const float4* vp = (const float4*)(&skv[m * 320 + 160 + h * 20]);
    float4 v0 = vp[0], v1 = vp[1], v2 = vp[2], v3 = vp[3];
    oa[0] = fmaf(p, v0.x, oa[0]);   oa[1] = fmaf(p, v0.y, oa[1]);
    oa[2] = fmaf(p, v0.z, oa[2]);   oa[3] = fmaf(p, v0.w, oa[3]);
    oa[4] = fmaf(p, v1.x, oa[4]);   oa[5] = fmaf(p, v1.y, oa[5]);
    oa[6] = fmaf(p, v1.z, oa[6]);   oa[7] = fmaf(p, v1.w, oa[7]);
    oa[8] = fmaf(p, v2.x, oa[8]);   oa[9] = fmaf(p, v2.y, oa[9]);
    oa[10] = fmaf(p, v2.z, oa[10]); oa[11] = fmaf(p, v2.w, oa[11]);
    oa[12] = fmaf(p, v3.x, oa[12]); oa[13] = fmaf(p, v3.y, oa[13]);
    oa[14] = fmaf(p, v3.z, oa[14]); oa[15] = fmaf(p, v3.w, oa[15]);
  }
  ushort8v w0, w1;
#pragma unroll
  for (int i = 0; i < 8; ++i) { w0[i] = f2bf(oa[i]); w1[i] = f2bf(oa[8 + i]); }
  const size_t r = (size_t)(rl * B_ + b) * N_ + n;
  const int m = (int)(r & 127);
  unsigned short* base = oimg + (r >> 7) * 16384;
  *(ushort8v*)(base + (size_t)(m * 16 + ((2 * h) ^ (m & 7))) * 8) = w0;
  *(ushort8v*)(base + (size_t)(m * 16 + ((2 * h + 1) ^ (m & 7))) * 8) = w1;
}

// ---------------------------------------------------------------------------
// sattn: spatial attention (K=8 gather). R7: XCD-pinned slab scheduling —
// grid 8(xcd) x 16(lb-local) x 32(chunk); assuming hw XCD = blockIdx%8,
// each XCD walks its 16 lb-slabs sequentially so the concurrent gather
// working set (~3-8 slabs x 512KB) fits its 4MiB L2. Full k+v preload
// (32 independent 16B loads in flight) before any compute.
// ---------------------------------------------------------------------------
__global__ __launch_bounds__(256) void sattn_kernel(
    const unsigned short* __restrict__ qkv, const int* __restrict__ route,
    unsigned short* __restrict__ oimg) {
  const int t = threadIdx.x;
  const int bb = blockIdx.x;
  const int xcd = bb & 7;
  const int idx = bb >> 3;
  const int lb = (idx >> 5) * 8 + xcd;  // 0..127
  const int chunk = idx & 31;
  const int rl = t >> 3, h = t & 7;
  const int nrow = chunk * 32 + rl;
  if (nrow >= N_) return;  // chunk 31 covers 8 rows
  const int n = nrow;
  const int r = lb * N_ + n;
  float q[16];
  {
    const unsigned short* qp = qkv + (size_t)r * 384 + h * DH_;
    ushort8v q0 = *(const ushort8v*)qp;
    ushort8v q1 = *(const ushort8v*)(qp + 8);
#pragma unroll
    for (int i = 0; i < 8; ++i) { q[i] = bf2f(q0[i]); q[8 + i] = bf2f(q1[i]); }
  }
  int nb[KN_];
#pragma unroll
  for (int kk = 0; kk < KN_; ++kk) nb[kk] = route[n * KN_ + kk];
  // full preload: all k and v segments issued before any FMA
  ushort8v kr[KN_][2], vr[KN_][2];
#pragma unroll
  for (int kk = 0; kk < KN_; ++kk) {
    const unsigned short* base = qkv + ((size_t)lb * N_ + nb[kk]) * 384;
    const unsigned short* kp = base + 128 + h * DH_;
    const unsigned short* vp = base + 256 + h * DH_;
    kr[kk][0] = *(const ushort8v*)kp;
    kr[kk][1] = *(const ushort8v*)(kp + 8);
    vr[kk][0] = *(const ushort8v*)vp;
    vr[kk][1] = *(const ushort8v*)(vp + 8);
  }
  float sc[KN_];
  float mx = -1e30f;
#pragma unroll
  for (int kk = 0; kk < KN_; ++kk) {
    float d = 0.f;
#pragma unroll
    for (int i = 0; i < 8; ++i) {
      d = fmaf(q[i], bf2f(kr[kk][0][i]), d);
      d = fmaf(q[8 + i], bf2f(kr[kk][1][i]), d);
    }
    d *= 0.25f;
    sc[kk] = d;
    mx = fmaxf(mx, d);
  }
  float ssum = 0.f;
#pragma unroll
  for (int kk = 0; kk < KN_; ++kk) { sc[kk] = __expf(sc[kk] - mx); ssum += sc[kk]; }
  float inv = 1.f / ssum;
  float oa[16];
#pragma unroll
  for (int i = 0; i < 16; ++i) oa[i] = 0.f;
#pragma unroll
  for (int kk = 0; kk < KN_; ++kk) {
    float p = sc[kk] * inv;
#pragma unroll
    for (int i = 0; i < 8; ++i) {
      oa[i] = fmaf(p, bf2f(vr[kk][0][i]), oa[i]);
      oa[8 + i] = fmaf(p, bf2f(vr[kk][1][i]), oa[8 + i]);
    }
  }
  ushort8v w0, w1;
#pragma unroll
  for (int i = 0; i < 8; ++i) { w0[i] = f2bf(oa[i]); w1[i] = f2bf(oa[8 + i]); }
  const int m = r & 127;
  unsigned short* base = oimg + (size_t)(r >> 7) * 16384;
  *(ushort8v*)(base + (size_t)(m * 16 + ((2 * h) ^ (m & 7))) * 8) = w0;
  *(ushort8v*)(base + (size_t)(m * 16 + ((2 * h + 1) ^ (m & 7))) * 8) = w1;
}

// ---------------------------------------------------------------------------
// final_mfma: out(M,128) fp32 = o_t@Wt^T + o_s@Ws^T + (bt+bs).
// Two K=128 phases, both sides DMA-staged from pre-swizzled images.
// ---------------------------------------------------------------------------
__global__ __launch_bounds__(256) void final_mfma(
    const unsigned short* __restrict__ otimg,
    const unsigned short* __restrict__ osimg,
    const unsigned short* __restrict__ wtimg,
    const unsigned short* __restrict__ wsimg, const float* __restrict__ bt,
    const float* __restrict__ bs, float* __restrict__ out) {
  __shared__ unsigned short As[128 * 128];
  __shared__ unsigned short Bs[128 * 128];
  const int t = threadIdx.x;
  const int bm = blockIdx.x;
  const int wave = t >> 6, lane = t & 63;
  const int wm = (wave >> 1) * 64, wn = (wave & 1) * 64;
  const int lq = lane >> 4, l16 = lane & 15;
  floatx4 acc[4][4] = {};
#pragma unroll
  for (int p = 0; p < 2; ++p) {
    if (p) __syncthreads();
    const unsigned short* aSrc = (p ? osimg : otimg) + (size_t)bm * 16384;
    const unsigned short* bSrc = p ? wsimg : wtimg;
#pragma unroll
    for (int it = 0; it < 8; ++it) {
      int gi = it * 256 + t;
      gload_lds16(aSrc + (size_t)gi * 8, &As[gi * 8]);
      gload_lds16(bSrc + (size_t)gi * 8, &Bs[gi * 8]);
    }
    __syncthreads();
#pragma unroll
    for (int kk = 0; kk < 4; ++kk) {
      int g = kk * 4 + lq;
      short8 a[4], b[4];
#pragma unroll
      for (int i = 0; i < 4; ++i) {
        int ma = wm + i * 16 + l16;
        a[i] = *(const short8*)(&As[(ma * 16 + (g ^ (ma & 7))) * 8]);
        int nb = wn + i * 16 + l16;
        b[i] = *(const short8*)(&Bs[(nb * 16 + (g ^ (nb & 7))) * 8]);
      }
#pragma unroll
      for (int i = 0; i < 4; ++i)
#pragma unroll
        for (int j = 0; j < 4; ++j)
          acc[i][j] = __builtin_amdgcn_mfma_f32_16x16x32_bf16(a[i], b[j],
                                                              acc[i][j], 0, 0, 0);
    }
  }
  const size_t rowBase = (size_t)bm * 128 + wm;
#pragma unroll
  for (int j = 0; j < 4; ++j) {
    int col = wn + j * 16 + l16;
    float bb = bt[col] + bs[col];
#pragma unroll
    for (int i = 0; i < 4; ++i) {
#pragma unroll
      for (int r = 0; r < 4; ++r) {
        size_t row = rowBase + i * 16 + lq * 4 + r;
        out[row * 128 + col] = acc[i][j][r] + bb;
      }
    }
  }
}

extern "C" void kernel_launch(void* const* d_in, const int* in_sizes, int n_in,
                              void* d_out, int out_size, void* d_ws,
                              size_t ws_size, hipStream_t stream) {
  const float* x = (const float*)d_in[0];
  const int* route = (const int*)d_in[1];
  const float* t_in_w = (const float*)d_in[2];
  const float* t_in_b = (const float*)d_in[3];
  const float* t_out_w = (const float*)d_in[4];
  const float* t_out_b = (const float*)d_in[5];
  const float* s_in_w = (const float*)d_in[6];
  const float* s_in_b = (const float*)d_in[7];
  const float* s_out_w = (const float*)d_in[8];
  const float* s_out_b = (const float*)d_in[9];
  float* out = (float*)d_out;
  // ws (ushorts): ximg [M*128] | qkv [M*384] | o_t img [M*128] | wimg [8*16384]
  // o_s img aliases ximg (dead after proj_s reads it). Total 164.1 MB.
  unsigned short* ximg = (unsigned short*)d_ws;
  unsigned short* qkv = ximg + (size_t)M_ * 128;
  unsigned short* o_t = qkv + (size_t)M_ * 384;
  unsigned short* wimg = o_t + (size_t)M_ * 128;
  unsigned short* o_s = ximg;  // alias

  prep_kernel<<<1008, 256, 0, stream>>>(x, t_in_w, s_in_w, t_out_w, s_out_w,
                                        ximg, wimg);
  proj_mfma<<<(M_ / 128) * 3, 256, 0, stream>>>(ximg, wimg, t_in_b, qkv);
  tattn_kernel<<<B_ * N_, 256, 0, stream>>>(qkv, o_t);
  proj_mfma<<<(M_ / 128) * 3, 256, 0, stream>>>(ximg, wimg + 3 * 16384,
                                                s_in_b, qkv);
  sattn_kernel<<<8 * 16 * 32, 256, 0, stream>>>(qkv, route, o_s);
  final_mfma<<<M_ / 128, 256, 0, stream>>>(o_t, o_s, wimg + 6 * 16384,
                                           wimg + 7 * 16384, t_out_b, s_out_b,
                                           out);
}